// Round 1
// baseline (3195.990 us; speedup 1.0000x reference)
//
#include <hip/hip_runtime.h>
#include <math.h>

#define D 128
#define RPB 32          // rows per block in the GEMM kernel
#define ALPHA 0.1f
#define LAMDA 0.5f

// ---------------- K1: A = W^T W + 1e-4 I  (tiny) ----------------
__global__ __launch_bounds__(256) void wtw_kernel(const float* __restrict__ W,
                                                  float* __restrict__ A) {
    int idx = blockIdx.x * blockDim.x + threadIdx.x;   // 16384 threads
    int i = idx >> 7, j = idx & (D - 1);
    float acc = (i == j) ? 1e-4f : 0.0f;
#pragma unroll 4
    for (int k = 0; k < D; ++k) acc = fmaf(W[k * D + i], W[k * D + j], acc);
    A[idx] = acc;
}

// ---------------- K2: one-block Cholesky + forward solve + build M --------
// S is stored TRANSPOSED (S[a][b] = A[b][a]); A symmetric so load is direct.
// This makes every per-thread column access land on distinct banks (lane t ->
// bank t%32, 2-way = free) instead of a 32-way conflict.
__global__ __launch_bounds__(256) void chol_solve_kernel(const float* __restrict__ A_in,
                                                         const float* __restrict__ W,
                                                         const int* __restrict__ lp,
                                                         float* __restrict__ LT,   // L^T, D*D
                                                         float* __restrict__ Mg) { // D*D
    __shared__ float S[D][D];          // exactly 64 KiB
    const int tid  = threadIdx.x;      // 0..255
    const int t    = tid & (D - 1);    // row/col owner
    const int half = tid >> 7;         // j-parity split for trailing update

    for (int i = tid; i < D * D; i += 256) ((float*)S)[i] = A_in[i];
    __syncthreads();

    // Right-looking Cholesky; thread t owns row t of A (= column t of S).
    for (int k = 0; k < D; ++k) {
        float dk  = S[k][k];                 // everyone reads pre-update value
        float lkk = sqrtf(dk);
        float inv = 1.0f / lkk;
        __syncthreads();
        if (half == 0) {
            if (t == k)      S[k][k] = lkk;
            else if (t > k)  S[k][t] *= inv;     // A[t][k] /= lkk
        }
        __syncthreads();
        if (t > k) {
            float ltk = S[k][t];                 // scaled A[t][k]
            for (int j = k + 1 + half; j <= t; j += 2)   // S[k][j] uniform per step
                S[j][t] -= ltk * S[k][j];        // A[t][j] -= A[t][k]*A[j][k]
        }
        __syncthreads();
    }

    // Spill L^T to global so LDS can be reused for Y.
    for (int i = tid; i < D * D; i += 256) LT[i] = ((float*)S)[i];
    __syncthreads();

    // Forward solve  Y = inv(L) W^T, column t per thread (threads 0..127).
    // L[i][j] = LT[j*D + i] (uniform address per step -> broadcast loads).
    if (half == 0) {
        for (int i = 0; i < D; ++i) {
            float acc = W[t * D + i];           // Wt[i][t] = W[t][i]
            float a0 = 0.f, a1 = 0.f, a2 = 0.f, a3 = 0.f;
            int j = 0;
            for (; j + 3 < i; j += 4) {
                a0 = fmaf(LT[(j + 0) * D + i], S[j + 0][t], a0);
                a1 = fmaf(LT[(j + 1) * D + i], S[j + 1][t], a1);
                a2 = fmaf(LT[(j + 2) * D + i], S[j + 2][t], a2);
                a3 = fmaf(LT[(j + 3) * D + i], S[j + 3][t], a3);
            }
            for (; j < i; ++j) a0 = fmaf(LT[j * D + i], S[j][t], a0);
            float y = (acc - ((a0 + a1) + (a2 + a3))) / LT[i * D + i];
            S[i][t] = y;                        // column t is private: no barrier
        }
    }
    __syncthreads();

    // M = theta * Y^T + (1-theta) * I ; M[k][c] = th*Y[c][k] + (1-th)*(k==c)
    float th = logf(LAMDA / (float)(*lp) + 1.0f);
    for (int idx = tid; idx < D * D; idx += 256) {
        int k = idx >> 7, c = idx & (D - 1);
        float m = th * S[c][k];
        if (k == c) m += 1.0f - th;
        Mg[idx] = m;
    }
}

// ---------------- K3: SpMM  hi[r] += v * x[c]  (atomic scatter) ----------
__global__ __launch_bounds__(256) void spmm_kernel(const float* __restrict__ x,
                                                   const float* __restrict__ vals,
                                                   const int* __restrict__ rows,
                                                   const int* __restrict__ cols,
                                                   float* __restrict__ hi, int E) {
    int tid = blockIdx.x * blockDim.x + threadIdx.x;
    int e = tid >> 5;                 // 32 threads per edge
    if (e >= E) return;
    int q = tid & 31;                 // handles floats [4q, 4q+3]
    float v = vals[e];
    int c = cols[e];
    int r = rows[e];
    const float4 xv = *reinterpret_cast<const float4*>(x + (size_t)c * D + q * 4);
    float* h = hi + (size_t)r * D + q * 4;
    unsafeAtomicAdd(h + 0, v * xv.x);
    unsafeAtomicAdd(h + 1, v * xv.y);
    unsafeAtomicAdd(h + 2, v * xv.z);
    unsafeAtomicAdd(h + 3, v * xv.w);
}

// ---------------- K4: out = tanh((0.9*hi + 0.1*h0) @ M) ------------------
__global__ __launch_bounds__(256) void gemm_tanh_kernel(const float* __restrict__ hi,
                                                        const float* __restrict__ h0,
                                                        const float* __restrict__ Mg,
                                                        float* __restrict__ out) {
    __shared__ float Ms[64][D];        // 32 KiB: half of M (k-rows)
    __shared__ float Ss[RPB][D + 1];   // stride 129 -> conflict-free a-reads
    const int tid = threadIdx.x;
    const int r0  = blockIdx.x * RPB;

    // Stage S = 0.9*hi + 0.1*h0 for 32 rows (float4 global, scalar LDS).
    for (int i = tid; i < RPB * D / 4; i += 256) {
        int rr = (i * 4) / D, cc = (i * 4) % D;
        float4 a = *reinterpret_cast<const float4*>(hi + (size_t)(r0 + rr) * D + cc);
        float4 b = *reinterpret_cast<const float4*>(h0 + (size_t)(r0 + rr) * D + cc);
        Ss[rr][cc + 0] = 0.9f * a.x + 0.1f * b.x;
        Ss[rr][cc + 1] = 0.9f * a.y + 0.1f * b.y;
        Ss[rr][cc + 2] = 0.9f * a.z + 0.1f * b.z;
        Ss[rr][cc + 3] = 0.9f * a.w + 0.1f * b.w;
    }

    const int tc = tid & 15;           // cols [4tc..4tc+3] and [64+4tc..]
    const int tr = tid >> 4;           // rows 2tr, 2tr+1
    float acc[2][8] = {};

    for (int kb = 0; kb < 2; ++kb) {
        __syncthreads();               // S ready / previous Ms consumed
        for (int i = tid; i < 64 * D / 4; i += 256)
            reinterpret_cast<float4*>(&Ms[0][0])[i] =
                reinterpret_cast<const float4*>(Mg + kb * 64 * D)[i];
        __syncthreads();
#pragma unroll 8
        for (int kk = 0; kk < 64; ++kk) {
            int k = kb * 64 + kk;
            float4 b0 = *reinterpret_cast<const float4*>(&Ms[kk][tc * 4]);
            float4 b1 = *reinterpret_cast<const float4*>(&Ms[kk][64 + tc * 4]);
            float a0 = Ss[2 * tr][k];
            float a1 = Ss[2 * tr + 1][k];
            acc[0][0] = fmaf(a0, b0.x, acc[0][0]);
            acc[0][1] = fmaf(a0, b0.y, acc[0][1]);
            acc[0][2] = fmaf(a0, b0.z, acc[0][2]);
            acc[0][3] = fmaf(a0, b0.w, acc[0][3]);
            acc[0][4] = fmaf(a0, b1.x, acc[0][4]);
            acc[0][5] = fmaf(a0, b1.y, acc[0][5]);
            acc[0][6] = fmaf(a0, b1.z, acc[0][6]);
            acc[0][7] = fmaf(a0, b1.w, acc[0][7]);
            acc[1][0] = fmaf(a1, b0.x, acc[1][0]);
            acc[1][1] = fmaf(a1, b0.y, acc[1][1]);
            acc[1][2] = fmaf(a1, b0.z, acc[1][2]);
            acc[1][3] = fmaf(a1, b0.w, acc[1][3]);
            acc[1][4] = fmaf(a1, b1.x, acc[1][4]);
            acc[1][5] = fmaf(a1, b1.y, acc[1][5]);
            acc[1][6] = fmaf(a1, b1.z, acc[1][6]);
            acc[1][7] = fmaf(a1, b1.w, acc[1][7]);
        }
    }

#pragma unroll
    for (int rr = 0; rr < 2; ++rr) {
        int r = r0 + 2 * tr + rr;
        float4 o0, o1;
        o0.x = tanhf(acc[rr][0]); o0.y = tanhf(acc[rr][1]);
        o0.z = tanhf(acc[rr][2]); o0.w = tanhf(acc[rr][3]);
        o1.x = tanhf(acc[rr][4]); o1.y = tanhf(acc[rr][5]);
        o1.z = tanhf(acc[rr][6]); o1.w = tanhf(acc[rr][7]);
        *reinterpret_cast<float4*>(out + (size_t)r * D + tc * 4)      = o0;
        *reinterpret_cast<float4*>(out + (size_t)r * D + 64 + tc * 4) = o1;
    }
}

extern "C" void kernel_launch(void* const* d_in, const int* in_sizes, int n_in,
                              void* d_out, int out_size, void* d_ws, size_t ws_size,
                              hipStream_t stream) {
    const float* x  = (const float*)d_in[0];
    const float* h0 = (const float*)d_in[1];
    const float* W  = (const float*)d_in[2];
    const float* av = (const float*)d_in[3];
    const int*   ar = (const int*)d_in[4];
    const int*   ac = (const int*)d_in[5];
    const int*   lp = (const int*)d_in[6];
    float* out = (float*)d_out;

    const int nd = in_sizes[0];        // N*D = 12,800,000
    const int n  = nd / D;             // 100,000
    const int E  = in_sizes[3];        // 1,600,000

    float* ws = (float*)d_ws;
    float* A  = ws;                    // D*D
    float* LT = ws + D * D;            // D*D
    float* Mg = ws + 2 * D * D;        // D*D
    const size_t small = 3 * (size_t)D * D * sizeof(float);
    float* hi;
    if (ws_size >= small + (size_t)nd * sizeof(float)) {
        hi = ws + 3 * D * D;
    } else {
        // Fallback: use d_out as the f32 accumulator. Safe: the GEMM kernel
        // stages each block's 32 rows into LDS before writing them back.
        hi = out;
    }

    hipMemsetAsync(hi, 0, (size_t)nd * sizeof(float), stream);
    wtw_kernel<<<D * D / 256, 256, 0, stream>>>(W, A);
    spmm_kernel<<<(int)(((size_t)E * 32 + 255) / 256), 256, 0, stream>>>(x, av, ar, ac, hi, E);
    chol_solve_kernel<<<1, 256, 0, stream>>>(A, W, lp, LT, Mg);
    gemm_tanh_kernel<<<n / RPB, 256, 0, stream>>>(hi, h0, Mg, out);
}

// Round 2
// 996.396 us; speedup vs baseline: 3.2075x; 3.2075x over previous
//
#include <hip/hip_runtime.h>
#include <math.h>

#define D 128
#define RPB 32          // rows per block in the GEMM kernel
#define ALPHA 0.1f
#define LAMDA 0.5f

// ---------------- K1: A = W^T W + 1e-4 I  (tiny) ----------------
__global__ __launch_bounds__(256) void wtw_kernel(const float* __restrict__ W,
                                                  float* __restrict__ A) {
    int idx = blockIdx.x * blockDim.x + threadIdx.x;   // 16384 threads
    int i = idx >> 7, j = idx & (D - 1);
    float acc = (i == j) ? 1e-4f : 0.0f;
#pragma unroll 4
    for (int k = 0; k < D; ++k) acc = fmaf(W[k * D + i], W[k * D + j], acc);
    A[idx] = acc;
}

// ---------------- K2: one-block Cholesky + forward solve + build M --------
__global__ __launch_bounds__(256) void chol_solve_kernel(const float* __restrict__ A_in,
                                                         const float* __restrict__ W,
                                                         const int* __restrict__ lp,
                                                         float* __restrict__ LT,   // L^T, D*D
                                                         float* __restrict__ Mg) { // D*D
    __shared__ float S[D][D];          // exactly 64 KiB
    const int tid  = threadIdx.x;      // 0..255
    const int t    = tid & (D - 1);    // row/col owner
    const int half = tid >> 7;         // j-parity split for trailing update

    for (int i = tid; i < D * D; i += 256) ((float*)S)[i] = A_in[i];
    __syncthreads();

    for (int k = 0; k < D; ++k) {
        float dk  = S[k][k];
        float lkk = sqrtf(dk);
        float inv = 1.0f / lkk;
        __syncthreads();
        if (half == 0) {
            if (t == k)      S[k][k] = lkk;
            else if (t > k)  S[k][t] *= inv;
        }
        __syncthreads();
        if (t > k) {
            float ltk = S[k][t];
            for (int j = k + 1 + half; j <= t; j += 2)
                S[j][t] -= ltk * S[k][j];
        }
        __syncthreads();
    }

    for (int i = tid; i < D * D; i += 256) LT[i] = ((float*)S)[i];
    __syncthreads();

    if (half == 0) {
        for (int i = 0; i < D; ++i) {
            float acc = W[t * D + i];
            float a0 = 0.f, a1 = 0.f, a2 = 0.f, a3 = 0.f;
            int j = 0;
            for (; j + 3 < i; j += 4) {
                a0 = fmaf(LT[(j + 0) * D + i], S[j + 0][t], a0);
                a1 = fmaf(LT[(j + 1) * D + i], S[j + 1][t], a1);
                a2 = fmaf(LT[(j + 2) * D + i], S[j + 2][t], a2);
                a3 = fmaf(LT[(j + 3) * D + i], S[j + 3][t], a3);
            }
            for (; j < i; ++j) a0 = fmaf(LT[j * D + i], S[j][t], a0);
            float y = (acc - ((a0 + a1) + (a2 + a3))) / LT[i * D + i];
            S[i][t] = y;
        }
    }
    __syncthreads();

    float th = logf(LAMDA / (float)(*lp) + 1.0f);
    for (int idx = tid; idx < D * D; idx += 256) {
        int k = idx >> 7, c = idx & (D - 1);
        float m = th * S[c][k];
        if (k == c) m += 1.0f - th;
        Mg[idx] = m;
    }
}

// ---------------- CSR build: histogram -> scan -> scatter ----------------
__global__ __launch_bounds__(256) void hist_kernel(const int* __restrict__ rows,
                                                   int* __restrict__ cnt, int E) {
    int e = blockIdx.x * blockDim.x + threadIdx.x;
    if (e < E) atomicAdd(&cnt[rows[e]], 1);
}

// One-block in-place exclusive scan: rp[] holds counts on entry, exclusive
// prefix sums on exit. Each thread owns a contiguous chunk; cross-thread
// offsets via LDS Hillis-Steele over the 1024 chunk sums.
__global__ __launch_bounds__(1024) void scan_kernel(int* __restrict__ rp, int n) {
    __shared__ int ps[1024];
    const int tid = threadIdx.x;
    const int C = (n + 1023) >> 10;
    const int base = tid * C;
    int s = 0;
    for (int j = 0; j < C; ++j) {
        int idx = base + j;
        if (idx < n) s += rp[idx];
    }
    ps[tid] = s;
    __syncthreads();
    for (int off = 1; off < 1024; off <<= 1) {
        int v = (tid >= off) ? ps[tid - off] : 0;
        __syncthreads();
        ps[tid] += v;
        __syncthreads();
    }
    int run = ps[tid] - s;   // exclusive prefix of this chunk
    for (int j = 0; j < C; ++j) {
        int idx = base + j;
        if (idx >= n) break;
        int c = rp[idx];     // read count, then overwrite (own chunk only)
        rp[idx] = run;
        run += c;
    }
}

// Scatter edges into packed CSR. rp[r] is the running cursor (starts at the
// exclusive prefix); after this kernel rp[r] == end-of-row-r, and
// start-of-row-r == (r ? rp[r-1] : 0).
__global__ __launch_bounds__(256) void scatter_kernel(const float* __restrict__ vals,
                                                      const int* __restrict__ rows,
                                                      const int* __restrict__ cols,
                                                      int* __restrict__ rp,
                                                      uint2* __restrict__ csr, int E) {
    int e = blockIdx.x * blockDim.x + threadIdx.x;
    if (e >= E) return;
    int r = rows[e];
    int pos = atomicAdd(&rp[r], 1);
    uint2 p;
    p.x = (unsigned)cols[e];
    p.y = __float_as_uint(vals[e]);
    csr[pos] = p;
}

// ---------------- K3: gather SpMM + fused support scale ------------------
// S[r] = 0.9 * sum_j v_j * x[c_j]  +  0.1 * h0[r].  32 lanes per row, float4
// per lane (16 B/lane coalescing sweet spot). No atomics, one write per row.
__global__ __launch_bounds__(256) void spmm_gather_kernel(const float* __restrict__ x,
                                                          const float* __restrict__ h0,
                                                          const uint2* __restrict__ csr,
                                                          const int* __restrict__ rp,
                                                          float* __restrict__ S, int n) {
    const int tid = threadIdx.x;
    const int r = blockIdx.x * 8 + (tid >> 5);
    if (r >= n) return;
    const int q = tid & 31;
    const int start = (r == 0) ? 0 : rp[r - 1];
    const int end = rp[r];

    float4 acc = make_float4(0.f, 0.f, 0.f, 0.f);
    int j = start;
    for (; j + 1 < end; j += 2) {                 // 2-deep MLP
        uint2 p0 = csr[j];
        uint2 p1 = csr[j + 1];
        float v0 = __uint_as_float(p0.y);
        float v1 = __uint_as_float(p1.y);
        const float4 x0 = *reinterpret_cast<const float4*>(x + (size_t)p0.x * D + q * 4);
        const float4 x1 = *reinterpret_cast<const float4*>(x + (size_t)p1.x * D + q * 4);
        acc.x = fmaf(v0, x0.x, acc.x); acc.y = fmaf(v0, x0.y, acc.y);
        acc.z = fmaf(v0, x0.z, acc.z); acc.w = fmaf(v0, x0.w, acc.w);
        acc.x = fmaf(v1, x1.x, acc.x); acc.y = fmaf(v1, x1.y, acc.y);
        acc.z = fmaf(v1, x1.z, acc.z); acc.w = fmaf(v1, x1.w, acc.w);
    }
    if (j < end) {
        uint2 p0 = csr[j];
        float v0 = __uint_as_float(p0.y);
        const float4 x0 = *reinterpret_cast<const float4*>(x + (size_t)p0.x * D + q * 4);
        acc.x = fmaf(v0, x0.x, acc.x); acc.y = fmaf(v0, x0.y, acc.y);
        acc.z = fmaf(v0, x0.z, acc.z); acc.w = fmaf(v0, x0.w, acc.w);
    }

    const float4 hb = *reinterpret_cast<const float4*>(h0 + (size_t)r * D + q * 4);
    float4 s;
    s.x = 0.9f * acc.x + 0.1f * hb.x;
    s.y = 0.9f * acc.y + 0.1f * hb.y;
    s.z = 0.9f * acc.z + 0.1f * hb.z;
    s.w = 0.9f * acc.w + 0.1f * hb.w;
    *reinterpret_cast<float4*>(S + (size_t)r * D + q * 4) = s;
}

// -------- Fallback K3 (atomic scatter) if workspace is too small ----------
__global__ __launch_bounds__(256) void spmm_atomic_kernel(const float* __restrict__ x,
                                                          const float* __restrict__ vals,
                                                          const int* __restrict__ rows,
                                                          const int* __restrict__ cols,
                                                          float* __restrict__ hi, int E) {
    int tid = blockIdx.x * blockDim.x + threadIdx.x;
    int e = tid >> 5;
    if (e >= E) return;
    int q = tid & 31;
    float v = vals[e];
    int c = cols[e];
    int r = rows[e];
    const float4 xv = *reinterpret_cast<const float4*>(x + (size_t)c * D + q * 4);
    float* h = hi + (size_t)r * D + q * 4;
    unsafeAtomicAdd(h + 0, v * xv.x);
    unsafeAtomicAdd(h + 1, v * xv.y);
    unsafeAtomicAdd(h + 2, v * xv.z);
    unsafeAtomicAdd(h + 3, v * xv.w);
}

__global__ __launch_bounds__(256) void blend_kernel(const float* __restrict__ hi,
                                                    const float* __restrict__ h0,
                                                    float* __restrict__ S, int nd4) {
    int i = blockIdx.x * blockDim.x + threadIdx.x;
    if (i >= nd4) return;
    float4 a = reinterpret_cast<const float4*>(hi)[i];
    float4 b = reinterpret_cast<const float4*>(h0)[i];
    float4 s;
    s.x = 0.9f * a.x + 0.1f * b.x;
    s.y = 0.9f * a.y + 0.1f * b.y;
    s.z = 0.9f * a.z + 0.1f * b.z;
    s.w = 0.9f * a.w + 0.1f * b.w;
    reinterpret_cast<float4*>(S)[i] = s;
}

// ---------------- K4: out = tanh(S @ M) ----------------------------------
__global__ __launch_bounds__(256) void gemm_tanh_kernel(const float* __restrict__ S,
                                                        const float* __restrict__ Mg,
                                                        float* __restrict__ out) {
    __shared__ float Ms[64][D];        // 32 KiB: half of M (k-rows)
    __shared__ float Ss[RPB][D + 1];   // stride 129 -> conflict-free a-reads
    const int tid = threadIdx.x;
    const int r0  = blockIdx.x * RPB;

    for (int i = tid; i < RPB * D / 4; i += 256) {
        int rr = (i * 4) / D, cc = (i * 4) % D;
        float4 a = *reinterpret_cast<const float4*>(S + (size_t)(r0 + rr) * D + cc);
        Ss[rr][cc + 0] = a.x;
        Ss[rr][cc + 1] = a.y;
        Ss[rr][cc + 2] = a.z;
        Ss[rr][cc + 3] = a.w;
    }

    const int tc = tid & 15;
    const int tr = tid >> 4;
    float acc[2][8] = {};

    for (int kb = 0; kb < 2; ++kb) {
        __syncthreads();
        for (int i = tid; i < 64 * D / 4; i += 256)
            reinterpret_cast<float4*>(&Ms[0][0])[i] =
                reinterpret_cast<const float4*>(Mg + kb * 64 * D)[i];
        __syncthreads();
#pragma unroll 8
        for (int kk = 0; kk < 64; ++kk) {
            int k = kb * 64 + kk;
            float4 b0 = *reinterpret_cast<const float4*>(&Ms[kk][tc * 4]);
            float4 b1 = *reinterpret_cast<const float4*>(&Ms[kk][64 + tc * 4]);
            float a0 = Ss[2 * tr][k];
            float a1 = Ss[2 * tr + 1][k];
            acc[0][0] = fmaf(a0, b0.x, acc[0][0]);
            acc[0][1] = fmaf(a0, b0.y, acc[0][1]);
            acc[0][2] = fmaf(a0, b0.z, acc[0][2]);
            acc[0][3] = fmaf(a0, b0.w, acc[0][3]);
            acc[0][4] = fmaf(a0, b1.x, acc[0][4]);
            acc[0][5] = fmaf(a0, b1.y, acc[0][5]);
            acc[0][6] = fmaf(a0, b1.z, acc[0][6]);
            acc[0][7] = fmaf(a0, b1.w, acc[0][7]);
            acc[1][0] = fmaf(a1, b0.x, acc[1][0]);
            acc[1][1] = fmaf(a1, b0.y, acc[1][1]);
            acc[1][2] = fmaf(a1, b0.z, acc[1][2]);
            acc[1][3] = fmaf(a1, b0.w, acc[1][3]);
            acc[1][4] = fmaf(a1, b1.x, acc[1][4]);
            acc[1][5] = fmaf(a1, b1.y, acc[1][5]);
            acc[1][6] = fmaf(a1, b1.z, acc[1][6]);
            acc[1][7] = fmaf(a1, b1.w, acc[1][7]);
        }
    }

#pragma unroll
    for (int rr = 0; rr < 2; ++rr) {
        int r = r0 + 2 * tr + rr;
        float4 o0, o1;
        o0.x = tanhf(acc[rr][0]); o0.y = tanhf(acc[rr][1]);
        o0.z = tanhf(acc[rr][2]); o0.w = tanhf(acc[rr][3]);
        o1.x = tanhf(acc[rr][4]); o1.y = tanhf(acc[rr][5]);
        o1.z = tanhf(acc[rr][6]); o1.w = tanhf(acc[rr][7]);
        *reinterpret_cast<float4*>(out + (size_t)r * D + tc * 4)      = o0;
        *reinterpret_cast<float4*>(out + (size_t)r * D + 64 + tc * 4) = o1;
    }
}

extern "C" void kernel_launch(void* const* d_in, const int* in_sizes, int n_in,
                              void* d_out, int out_size, void* d_ws, size_t ws_size,
                              hipStream_t stream) {
    const float* x  = (const float*)d_in[0];
    const float* h0 = (const float*)d_in[1];
    const float* W  = (const float*)d_in[2];
    const float* av = (const float*)d_in[3];
    const int*   ar = (const int*)d_in[4];
    const int*   ac = (const int*)d_in[5];
    const int*   lp = (const int*)d_in[6];
    float* out = (float*)d_out;

    const int nd = in_sizes[0];        // N*D
    const int n  = nd / D;             // N
    const int E  = in_sizes[3];

    char* wsb = (char*)d_ws;
    float* A  = (float*)wsb;                                   // D*D
    float* LT = A + D * D;                                     // D*D
    float* Mg = LT + D * D;                                    // D*D
    size_t off = 3 * (size_t)D * D * sizeof(float);

    int* rp = (int*)(wsb + off);                               // N ints
    off += (size_t)n * sizeof(int);
    off = (off + 15) & ~(size_t)15;
    uint2* csr = (uint2*)(wsb + off);                          // E uint2
    off += (size_t)E * sizeof(uint2);
    off = (off + 15) & ~(size_t)15;

    const size_t need_csr = off;
    const size_t need_S   = off + (size_t)nd * sizeof(float);

    if (ws_size >= need_csr) {
        float* S = (ws_size >= need_S) ? (float*)(wsb + off) : out;
        // CSR path: no float atomics.
        hipMemsetAsync(rp, 0, (size_t)n * sizeof(int), stream);
        hist_kernel<<<(E + 255) / 256, 256, 0, stream>>>(ar, rp, E);
        wtw_kernel<<<D * D / 256, 256, 0, stream>>>(W, A);     // overlap-free but cheap
        scan_kernel<<<1, 1024, 0, stream>>>(rp, n);
        scatter_kernel<<<(E + 255) / 256, 256, 0, stream>>>(av, ar, ac, rp, csr, E);
        chol_solve_kernel<<<1, 256, 0, stream>>>(A, W, lp, LT, Mg);
        spmm_gather_kernel<<<(n + 7) / 8, 256, 0, stream>>>(x, h0, csr, rp, S, n);
        gemm_tanh_kernel<<<n / RPB, 256, 0, stream>>>(S, Mg, out);
    } else {
        // Fallback: atomic scatter into out, blend in-place via ws if tiny.
        float* hi = out;
        hipMemsetAsync(hi, 0, (size_t)nd * sizeof(float), stream);
        wtw_kernel<<<D * D / 256, 256, 0, stream>>>(W, A);
        spmm_atomic_kernel<<<(int)(((size_t)E * 32 + 255) / 256), 256, 0, stream>>>(x, av, ar, ac, hi, E);
        chol_solve_kernel<<<1, 256, 0, stream>>>(A, W, lp, LT, Mg);
        blend_kernel<<<(nd / 4 + 255) / 256, 256, 0, stream>>>(hi, h0, hi, nd / 4);
        gemm_tanh_kernel<<<n / RPB, 256, 0, stream>>>(hi, Mg, out);
    }
}

// Round 3
// 859.564 us; speedup vs baseline: 3.7182x; 1.1592x over previous
//
#include <hip/hip_runtime.h>
#include <math.h>

#define D 128
#define RPB 64          // rows per block in the GEMM kernel
#define ALPHA 0.1f
#define LAMDA 0.5f

// ---------------- K1: A = W^T W + 1e-4 I  (tiny) ----------------
__global__ __launch_bounds__(256) void wtw_kernel(const float* __restrict__ W,
                                                  float* __restrict__ A) {
    int idx = blockIdx.x * blockDim.x + threadIdx.x;   // 16384 threads
    int i = idx >> 7, j = idx & (D - 1);
    float acc = (i == j) ? 1e-4f : 0.0f;
#pragma unroll 4
    for (int k = 0; k < D; ++k) acc = fmaf(W[k * D + i], W[k * D + j], acc);
    A[idx] = acc;
}

// ---------------- K2a: one-block Cholesky factorization ------------------
// S stored TRANSPOSED (S[a][b] = A[b][a]); after factoring, S[j][i] = L[i][j]
// for i>=j. Written flat to Lg (so Lg[j*D+i] = L[i][j]).
__global__ __launch_bounds__(256) void chol_factor_kernel(const float* __restrict__ A_in,
                                                          float* __restrict__ Lg) {
    __shared__ float S[D][D];          // 64 KiB
    const int tid  = threadIdx.x;      // 0..255
    const int t    = tid & (D - 1);    // column owner
    const int half = tid >> 7;         // j-parity split for trailing update

    for (int i = tid; i < D * D; i += 256) ((float*)S)[i] = A_in[i];
    __syncthreads();

    for (int k = 0; k < D; ++k) {
        float dk  = S[k][k];                 // pre-update value, read by all
        float lkk = sqrtf(dk);
        float inv = 1.0f / lkk;
        __syncthreads();
        if (half == 0) {
            if (t == k)      S[k][k] = lkk;
            else if (t > k)  S[k][t] *= inv;
        }
        __syncthreads();
        if (t > k) {
            float ltk = S[k][t];
            for (int j = k + 1 + half; j <= t; j += 2)   // S[k][j] uniform/bcast
                S[j][t] -= ltk * S[k][j];
        }
        __syncthreads();
    }

    for (int i = tid; i < D * D; i += 256) Lg[i] = ((float*)S)[i];
}

// ---------------- K2b: parallel triangular solve + build M ---------------
// Block c (128 blocks, 1 wave each) solves L y = W^T[:,c] wave-synchronously:
// lane j owns y_j and y_{j+64} in registers; per step i the partial products
// are butterfly-reduced via shfl_xor. Then writes M row c:
//   M[c][i] = th*Y[i][c] + (1-th)*(c==i)
__global__ __launch_bounds__(64) void solve_m_kernel(const float* __restrict__ Lg,
                                                     const float* __restrict__ W,
                                                     const int* __restrict__ lp,
                                                     float* __restrict__ Mg) {
    __shared__ float Lr[D][D + 1];     // Lr[i][j] = L[i][j]; +1 pad: row reads
    const int lane = threadIdx.x;      // 0..63   conflict-free, transposed
    const int c = blockIdx.x;          // stage writes stride-129 conflict-free

    for (int j = 0; j < D; ++j) {      // Lg[j*D+i] = L[i][j]
        Lr[lane][j]      = Lg[j * D + lane];
        Lr[lane + 64][j] = Lg[j * D + lane + 64];
    }
    __syncthreads();

    const float w_lo = W[c * D + lane];        // Wt[i][c] = W[c][i]
    const float w_hi = W[c * D + 64 + lane];
    const float dinv_lo = 1.0f / Lr[lane][lane];
    const float dinv_hi = 1.0f / Lr[lane + 64][lane + 64];
    float y_lo = 0.0f, y_hi = 0.0f;

    for (int i = 0; i < D; ++i) {
        float l0 = Lr[i][lane];                // consecutive lanes -> no conflict
        float l1 = Lr[i][lane + 64];
        float p = 0.0f;
        p += (lane < i)      ? l0 * y_lo : 0.0f;
        p += (lane + 64 < i) ? l1 * y_hi : 0.0f;
#pragma unroll
        for (int off = 32; off >= 1; off >>= 1) p += __shfl_xor(p, off);
        if (i < 64) {
            if (lane == i)      y_lo = (w_lo - p) * dinv_lo;
        } else {
            if (lane == i - 64) y_hi = (w_hi - p) * dinv_hi;
        }
    }

    const float th = logf(LAMDA / (float)(*lp) + 1.0f);
    float m_lo = th * y_lo + ((c == lane)      ? (1.0f - th) : 0.0f);
    float m_hi = th * y_hi + ((c == lane + 64) ? (1.0f - th) : 0.0f);
    Mg[c * D + lane]      = m_lo;
    Mg[c * D + 64 + lane] = m_hi;
}

// ---------------- CSR build: histogram -> scan -> scatter ----------------
__global__ __launch_bounds__(256) void hist_kernel(const int* __restrict__ rows,
                                                   int* __restrict__ cnt, int E) {
    int e = blockIdx.x * blockDim.x + threadIdx.x;
    if (e < E) atomicAdd(&cnt[rows[e]], 1);
}

__global__ __launch_bounds__(1024) void scan_kernel(int* __restrict__ rp, int n) {
    __shared__ int ps[1024];
    const int tid = threadIdx.x;
    const int C = (n + 1023) >> 10;
    const int base = tid * C;
    int s = 0;
    for (int j = 0; j < C; ++j) {
        int idx = base + j;
        if (idx < n) s += rp[idx];
    }
    ps[tid] = s;
    __syncthreads();
    for (int off = 1; off < 1024; off <<= 1) {
        int v = (tid >= off) ? ps[tid - off] : 0;
        __syncthreads();
        ps[tid] += v;
        __syncthreads();
    }
    int run = ps[tid] - s;   // exclusive prefix of this chunk
    for (int j = 0; j < C; ++j) {
        int idx = base + j;
        if (idx >= n) break;
        int cnt = rp[idx];
        rp[idx] = run;
        run += cnt;
    }
}

// After scatter: rp[r] == end of row r; start == (r ? rp[r-1] : 0).
__global__ __launch_bounds__(256) void scatter_kernel(const float* __restrict__ vals,
                                                      const int* __restrict__ rows,
                                                      const int* __restrict__ cols,
                                                      int* __restrict__ rp,
                                                      uint2* __restrict__ csr, int E) {
    int e = blockIdx.x * blockDim.x + threadIdx.x;
    if (e >= E) return;
    int r = rows[e];
    int pos = atomicAdd(&rp[r], 1);
    uint2 p;
    p.x = (unsigned)cols[e];
    p.y = __float_as_uint(vals[e]);
    csr[pos] = p;
}

// ---------------- K3: gather SpMM + fused support scale ------------------
__global__ __launch_bounds__(256) void spmm_gather_kernel(const float* __restrict__ x,
                                                          const float* __restrict__ h0,
                                                          const uint2* __restrict__ csr,
                                                          const int* __restrict__ rp,
                                                          float* __restrict__ S, int n) {
    const int tid = threadIdx.x;
    const int r = blockIdx.x * 8 + (tid >> 5);
    if (r >= n) return;
    const int q = tid & 31;
    const int start = (r == 0) ? 0 : rp[r - 1];
    const int end = rp[r];

    float4 acc = make_float4(0.f, 0.f, 0.f, 0.f);
    int j = start;
    for (; j + 1 < end; j += 2) {
        uint2 p0 = csr[j];
        uint2 p1 = csr[j + 1];
        float v0 = __uint_as_float(p0.y);
        float v1 = __uint_as_float(p1.y);
        const float4 x0 = *reinterpret_cast<const float4*>(x + (size_t)p0.x * D + q * 4);
        const float4 x1 = *reinterpret_cast<const float4*>(x + (size_t)p1.x * D + q * 4);
        acc.x = fmaf(v0, x0.x, acc.x); acc.y = fmaf(v0, x0.y, acc.y);
        acc.z = fmaf(v0, x0.z, acc.z); acc.w = fmaf(v0, x0.w, acc.w);
        acc.x = fmaf(v1, x1.x, acc.x); acc.y = fmaf(v1, x1.y, acc.y);
        acc.z = fmaf(v1, x1.z, acc.z); acc.w = fmaf(v1, x1.w, acc.w);
    }
    if (j < end) {
        uint2 p0 = csr[j];
        float v0 = __uint_as_float(p0.y);
        const float4 x0 = *reinterpret_cast<const float4*>(x + (size_t)p0.x * D + q * 4);
        acc.x = fmaf(v0, x0.x, acc.x); acc.y = fmaf(v0, x0.y, acc.y);
        acc.z = fmaf(v0, x0.z, acc.z); acc.w = fmaf(v0, x0.w, acc.w);
    }

    const float4 hb = *reinterpret_cast<const float4*>(h0 + (size_t)r * D + q * 4);
    float4 s;
    s.x = 0.9f * acc.x + 0.1f * hb.x;
    s.y = 0.9f * acc.y + 0.1f * hb.y;
    s.z = 0.9f * acc.z + 0.1f * hb.z;
    s.w = 0.9f * acc.w + 0.1f * hb.w;
    *reinterpret_cast<float4*>(S + (size_t)r * D + q * 4) = s;
}

// -------- Fallback K3 (atomic scatter) if workspace is too small ----------
__global__ __launch_bounds__(256) void spmm_atomic_kernel(const float* __restrict__ x,
                                                          const float* __restrict__ vals,
                                                          const int* __restrict__ rows,
                                                          const int* __restrict__ cols,
                                                          float* __restrict__ hi, int E) {
    int tid = blockIdx.x * blockDim.x + threadIdx.x;
    int e = tid >> 5;
    if (e >= E) return;
    int q = tid & 31;
    float v = vals[e];
    int c = cols[e];
    int r = rows[e];
    const float4 xv = *reinterpret_cast<const float4*>(x + (size_t)c * D + q * 4);
    float* h = hi + (size_t)r * D + q * 4;
    unsafeAtomicAdd(h + 0, v * xv.x);
    unsafeAtomicAdd(h + 1, v * xv.y);
    unsafeAtomicAdd(h + 2, v * xv.z);
    unsafeAtomicAdd(h + 3, v * xv.w);
}

__global__ __launch_bounds__(256) void blend_kernel(const float* __restrict__ hi,
                                                    const float* __restrict__ h0,
                                                    float* __restrict__ S, int nd4) {
    int i = blockIdx.x * blockDim.x + threadIdx.x;
    if (i >= nd4) return;
    float4 a = reinterpret_cast<const float4*>(hi)[i];
    float4 b = reinterpret_cast<const float4*>(h0)[i];
    float4 s;
    s.x = 0.9f * a.x + 0.1f * b.x;
    s.y = 0.9f * a.y + 0.1f * b.y;
    s.z = 0.9f * a.z + 0.1f * b.z;
    s.w = 0.9f * a.w + 0.1f * b.w;
    reinterpret_cast<float4*>(S)[i] = s;
}

// ---------------- K4: out = tanh(S @ M), 64 rows/block, 4x8/thread -------
__global__ __launch_bounds__(256) void gemm_tanh_kernel(const float* __restrict__ S,
                                                        const float* __restrict__ Mg,
                                                        float* __restrict__ out, int n) {
    __shared__ float Ms[64][D];        // 32 KiB: half of M (k-rows)
    __shared__ float Ss[RPB][D + 1];   // 33 KiB, stride 129 conflict-free
    const int tid = threadIdx.x;
    const int r0  = blockIdx.x * RPB;

    for (int i = tid; i < RPB * D / 4; i += 256) {
        int rr = (i * 4) / D, cc = (i * 4) & (D - 1);
        int r = r0 + rr;
        float4 a = (r < n) ? *reinterpret_cast<const float4*>(S + (size_t)r * D + cc)
                           : make_float4(0.f, 0.f, 0.f, 0.f);
        Ss[rr][cc + 0] = a.x;
        Ss[rr][cc + 1] = a.y;
        Ss[rr][cc + 2] = a.z;
        Ss[rr][cc + 3] = a.w;
    }

    const int tc = tid & 15;           // cols [4tc..] and [64+4tc..]
    const int tr = tid >> 4;           // rows 4tr .. 4tr+3
    float acc[4][8] = {};

    for (int kb = 0; kb < 2; ++kb) {
        __syncthreads();               // S ready / previous Ms consumed
        for (int i = tid; i < 64 * D / 4; i += 256)
            reinterpret_cast<float4*>(&Ms[0][0])[i] =
                reinterpret_cast<const float4*>(Mg + kb * 64 * D)[i];
        __syncthreads();
#pragma unroll 4
        for (int kk = 0; kk < 64; ++kk) {
            int k = kb * 64 + kk;
            float4 b0 = *reinterpret_cast<const float4*>(&Ms[kk][tc * 4]);
            float4 b1 = *reinterpret_cast<const float4*>(&Ms[kk][64 + tc * 4]);
#pragma unroll
            for (int m = 0; m < 4; ++m) {
                float a = Ss[4 * tr + m][k];
                acc[m][0] = fmaf(a, b0.x, acc[m][0]);
                acc[m][1] = fmaf(a, b0.y, acc[m][1]);
                acc[m][2] = fmaf(a, b0.z, acc[m][2]);
                acc[m][3] = fmaf(a, b0.w, acc[m][3]);
                acc[m][4] = fmaf(a, b1.x, acc[m][4]);
                acc[m][5] = fmaf(a, b1.y, acc[m][5]);
                acc[m][6] = fmaf(a, b1.z, acc[m][6]);
                acc[m][7] = fmaf(a, b1.w, acc[m][7]);
            }
        }
    }

#pragma unroll
    for (int m = 0; m < 4; ++m) {
        int r = r0 + 4 * tr + m;
        if (r >= n) continue;
        float4 o0, o1;
        o0.x = tanhf(acc[m][0]); o0.y = tanhf(acc[m][1]);
        o0.z = tanhf(acc[m][2]); o0.w = tanhf(acc[m][3]);
        o1.x = tanhf(acc[m][4]); o1.y = tanhf(acc[m][5]);
        o1.z = tanhf(acc[m][6]); o1.w = tanhf(acc[m][7]);
        *reinterpret_cast<float4*>(out + (size_t)r * D + tc * 4)      = o0;
        *reinterpret_cast<float4*>(out + (size_t)r * D + 64 + tc * 4) = o1;
    }
}

extern "C" void kernel_launch(void* const* d_in, const int* in_sizes, int n_in,
                              void* d_out, int out_size, void* d_ws, size_t ws_size,
                              hipStream_t stream) {
    const float* x  = (const float*)d_in[0];
    const float* h0 = (const float*)d_in[1];
    const float* W  = (const float*)d_in[2];
    const float* av = (const float*)d_in[3];
    const int*   ar = (const int*)d_in[4];
    const int*   ac = (const int*)d_in[5];
    const int*   lp = (const int*)d_in[6];
    float* out = (float*)d_out;

    const int nd = in_sizes[0];        // N*D
    const int n  = nd / D;             // N
    const int E  = in_sizes[3];

    char* wsb = (char*)d_ws;
    float* A  = (float*)wsb;                                   // D*D
    float* Lg = A + D * D;                                     // D*D
    float* Mg = Lg + D * D;                                    // D*D
    size_t off = 3 * (size_t)D * D * sizeof(float);

    int* rp = (int*)(wsb + off);                               // N ints
    off += (size_t)n * sizeof(int);
    off = (off + 15) & ~(size_t)15;
    uint2* csr = (uint2*)(wsb + off);                          // E uint2
    off += (size_t)E * sizeof(uint2);
    off = (off + 15) & ~(size_t)15;

    const size_t need_csr = off;
    const size_t need_S   = off + (size_t)nd * sizeof(float);
    const int gemm_grid = (n + RPB - 1) / RPB;

    if (ws_size >= need_csr) {
        float* S = (ws_size >= need_S) ? (float*)(wsb + off) : out;
        hipMemsetAsync(rp, 0, (size_t)n * sizeof(int), stream);
        hist_kernel<<<(E + 255) / 256, 256, 0, stream>>>(ar, rp, E);
        wtw_kernel<<<D * D / 256, 256, 0, stream>>>(W, A);
        scan_kernel<<<1, 1024, 0, stream>>>(rp, n);
        scatter_kernel<<<(E + 255) / 256, 256, 0, stream>>>(av, ar, ac, rp, csr, E);
        chol_factor_kernel<<<1, 256, 0, stream>>>(A, Lg);
        solve_m_kernel<<<D, 64, 0, stream>>>(Lg, W, lp, Mg);
        spmm_gather_kernel<<<(n + 7) / 8, 256, 0, stream>>>(x, h0, csr, rp, S, n);
        gemm_tanh_kernel<<<gemm_grid, 256, 0, stream>>>(S, Mg, out, n);
    } else {
        float* hi = out;
        hipMemsetAsync(hi, 0, (size_t)nd * sizeof(float), stream);
        wtw_kernel<<<D * D / 256, 256, 0, stream>>>(W, A);
        spmm_atomic_kernel<<<(int)(((size_t)E * 32 + 255) / 256), 256, 0, stream>>>(x, av, ar, ac, hi, E);
        chol_factor_kernel<<<1, 256, 0, stream>>>(A, Lg);
        solve_m_kernel<<<D, 64, 0, stream>>>(Lg, W, lp, Mg);
        blend_kernel<<<(nd / 4 + 255) / 256, 256, 0, stream>>>(hi, h0, hi, nd / 4);
        gemm_tanh_kernel<<<gemm_grid, 256, 0, stream>>>(hi, Mg, out, n);
    }
}

// Round 4
// 678.097 us; speedup vs baseline: 4.7132x; 1.2676x over previous
//
#include <hip/hip_runtime.h>
#include <math.h>

#define D 128
#define NB 16           // Cholesky panel width
#define RPB 64          // rows per block in the GEMM kernel
#define ALPHA 0.1f
#define LAMDA 0.5f

// ---------------- K1: A = W^T W + 1e-4 I  (tiny) ----------------
__global__ __launch_bounds__(256) void wtw_kernel(const float* __restrict__ W,
                                                  float* __restrict__ A) {
    int idx = blockIdx.x * blockDim.x + threadIdx.x;   // 16384 threads
    int i = idx >> 7, j = idx & (D - 1);
    float acc = (i == j) ? 1e-4f : 0.0f;
#pragma unroll 4
    for (int k = 0; k < D; ++k) acc = fmaf(W[k * D + i], W[k * D + j], acc);
    A[idx] = acc;
}

// ---------------- K2a: one-block BLOCKED Cholesky (NB=16) ----------------
// Storage: matrix element (row i, col j), i>=j, lives at S[j][i] (column j of
// L is contiguous). A symmetric -> flat load works. Output Lg[j*D+i]=L[i][j].
__global__ __launch_bounds__(256) void chol_factor_kernel(const float* __restrict__ A_in,
                                                          float* __restrict__ Lg) {
    __shared__ float S[D][D];          // 64 KiB
    __shared__ float dinvS[NB];        // 1/L[k][k] for current diag block
    const int tid = threadIdx.x;       // 0..255
    const int tx = tid & 15;           // matrix row offset inside a tile
    const int ty = tid >> 4;           // matrix col offset inside a tile

    for (int i = tid; i < D * D; i += 256) ((float*)S)[i] = A_in[i];
    __syncthreads();

    for (int s = 0; s < D / NB; ++s) {
        const int b = s * NB;

        // ---- (a) factor diagonal block: element (b+tx, b+ty) per thread ----
        for (int k = 0; k < NB; ++k) {
            // reads (values from step k-1, sealed by trailing barrier)
            float dk  = S[b + k][b + k];
            float a_i = S[b + k][b + tx];    // A[b+tx][b+k]
            float a_j = S[b + k][b + ty];    // A[b+ty][b+k]
            float lkk  = sqrtf(dk);
            float inv  = 1.0f / lkk;
            float invd = inv * inv;          // 1/dk
            __syncthreads();
            if (ty == 0) {
                if (tx == k)       { S[b + k][b + k] = lkk; dinvS[k] = inv; }
                else if (tx > k)     S[b + k][b + tx] = a_i * inv;   // L[b+tx][b+k]
            }
            if (ty > k && tx >= ty)
                S[b + ty][b + tx] -= a_i * (a_j * invd);  // rank-1 on remainder
            __syncthreads();
        }

        const int m = D - b - NB;          // rows below the diagonal block

        // ---- (b) panel solve: L21 row per thread (forward substitution) ----
        if (m > 0 && tid < m) {
            const int r = b + NB + tid;
            float y[NB];
#pragma unroll
            for (int k = 0; k < NB; ++k) y[k] = S[b + k][r];   // A[r][b+k]
#pragma unroll
            for (int k = 0; k < NB; ++k) {
                float acc = y[k];
#pragma unroll
                for (int q = 0; q < NB; ++q)
                    if (q < k) acc -= S[b + q][b + k] * y[q];  // L11[k][q] bcast
                y[k] = acc * dinvS[k];
            }
#pragma unroll
            for (int k = 0; k < NB; ++k) S[b + k][r] = y[k];   // L[r][b+k]
        }
        __syncthreads();

        // ---- (c) trailing update: A22 -= L21 L21^T, 16x16 tile per iter ----
        const int nt = m >> 4;
        for (int tc = 0; tc < nt; ++tc) {
            for (int tr = tc; tr < nt; ++tr) {
                const int c = b + NB + tc * 16 + ty;
                const int r = b + NB + tr * 16 + tx;
                if (r >= c) {
                    float acc = S[c][r];
#pragma unroll
                    for (int k = 0; k < NB; ++k)
                        acc -= S[b + k][r] * S[b + k][c];
                    S[c][r] = acc;
                }
            }
        }
        __syncthreads();
    }

    for (int i = tid; i < D * D; i += 256) Lg[i] = ((float*)S)[i];
}

// ---------------- K2b: parallel triangular solve + build M ---------------
// Block c (128 blocks, 1 wave each) solves L y = W^T[:,c] wave-synchronously.
__global__ __launch_bounds__(64) void solve_m_kernel(const float* __restrict__ Lg,
                                                     const float* __restrict__ W,
                                                     const int* __restrict__ lp,
                                                     float* __restrict__ Mg) {
    __shared__ float Lr[D][D + 1];     // Lr[i][j] = L[i][j]; +1 pad
    const int lane = threadIdx.x;      // 0..63
    const int c = blockIdx.x;

    for (int j = 0; j < D; ++j) {      // Lg[j*D+i] = L[i][j]
        Lr[lane][j]      = Lg[j * D + lane];
        Lr[lane + 64][j] = Lg[j * D + lane + 64];
    }
    __syncthreads();

    const float w_lo = W[c * D + lane];
    const float w_hi = W[c * D + 64 + lane];
    const float dinv_lo = 1.0f / Lr[lane][lane];
    const float dinv_hi = 1.0f / Lr[lane + 64][lane + 64];
    float y_lo = 0.0f, y_hi = 0.0f;

    for (int i = 0; i < D; ++i) {
        float l0 = Lr[i][lane];
        float l1 = Lr[i][lane + 64];
        float p = 0.0f;
        p += (lane < i)      ? l0 * y_lo : 0.0f;
        p += (lane + 64 < i) ? l1 * y_hi : 0.0f;
#pragma unroll
        for (int off = 32; off >= 1; off >>= 1) p += __shfl_xor(p, off);
        if (i < 64) {
            if (lane == i)      y_lo = (w_lo - p) * dinv_lo;
        } else {
            if (lane == i - 64) y_hi = (w_hi - p) * dinv_hi;
        }
    }

    const float th = logf(LAMDA / (float)(*lp) + 1.0f);
    float m_lo = th * y_lo + ((c == lane)      ? (1.0f - th) : 0.0f);
    float m_hi = th * y_hi + ((c == lane + 64) ? (1.0f - th) : 0.0f);
    Mg[c * D + lane]      = m_lo;
    Mg[c * D + 64 + lane] = m_hi;
}

// ---------------- CSR build: histogram -> scan -> scatter ----------------
__global__ __launch_bounds__(256) void hist_kernel(const int* __restrict__ rows,
                                                   int* __restrict__ cnt, int E) {
    int e = blockIdx.x * blockDim.x + threadIdx.x;
    if (e < E) atomicAdd(&cnt[rows[e]], 1);
}

__global__ __launch_bounds__(1024) void scan_kernel(int* __restrict__ rp, int n) {
    __shared__ int ps[1024];
    const int tid = threadIdx.x;
    const int C = (n + 1023) >> 10;
    const int base = tid * C;
    int s = 0;
    for (int j = 0; j < C; ++j) {
        int idx = base + j;
        if (idx < n) s += rp[idx];
    }
    ps[tid] = s;
    __syncthreads();
    for (int off = 1; off < 1024; off <<= 1) {
        int v = (tid >= off) ? ps[tid - off] : 0;
        __syncthreads();
        ps[tid] += v;
        __syncthreads();
    }
    int run = ps[tid] - s;   // exclusive prefix of this chunk
    for (int j = 0; j < C; ++j) {
        int idx = base + j;
        if (idx >= n) break;
        int cnt = rp[idx];
        rp[idx] = run;
        run += cnt;
    }
}

// After scatter: rp[r] == end of row r; start == (r ? rp[r-1] : 0).
__global__ __launch_bounds__(256) void scatter_kernel(const float* __restrict__ vals,
                                                      const int* __restrict__ rows,
                                                      const int* __restrict__ cols,
                                                      int* __restrict__ rp,
                                                      uint2* __restrict__ csr, int E) {
    int e = blockIdx.x * blockDim.x + threadIdx.x;
    if (e >= E) return;
    int r = rows[e];
    int pos = atomicAdd(&rp[r], 1);
    uint2 p;
    p.x = (unsigned)cols[e];
    p.y = __float_as_uint(vals[e]);
    csr[pos] = p;
}

// ---------------- K3: gather SpMM + fused support scale ------------------
__global__ __launch_bounds__(256) void spmm_gather_kernel(const float* __restrict__ x,
                                                          const float* __restrict__ h0,
                                                          const uint2* __restrict__ csr,
                                                          const int* __restrict__ rp,
                                                          float* __restrict__ S, int n) {
    const int tid = threadIdx.x;
    const int r = blockIdx.x * 8 + (tid >> 5);
    if (r >= n) return;
    const int q = tid & 31;
    const int start = (r == 0) ? 0 : rp[r - 1];
    const int end = rp[r];

    float4 acc = make_float4(0.f, 0.f, 0.f, 0.f);
    int j = start;
    for (; j + 1 < end; j += 2) {
        uint2 p0 = csr[j];
        uint2 p1 = csr[j + 1];
        float v0 = __uint_as_float(p0.y);
        float v1 = __uint_as_float(p1.y);
        const float4 x0 = *reinterpret_cast<const float4*>(x + (size_t)p0.x * D + q * 4);
        const float4 x1 = *reinterpret_cast<const float4*>(x + (size_t)p1.x * D + q * 4);
        acc.x = fmaf(v0, x0.x, acc.x); acc.y = fmaf(v0, x0.y, acc.y);
        acc.z = fmaf(v0, x0.z, acc.z); acc.w = fmaf(v0, x0.w, acc.w);
        acc.x = fmaf(v1, x1.x, acc.x); acc.y = fmaf(v1, x1.y, acc.y);
        acc.z = fmaf(v1, x1.z, acc.z); acc.w = fmaf(v1, x1.w, acc.w);
    }
    if (j < end) {
        uint2 p0 = csr[j];
        float v0 = __uint_as_float(p0.y);
        const float4 x0 = *reinterpret_cast<const float4*>(x + (size_t)p0.x * D + q * 4);
        acc.x = fmaf(v0, x0.x, acc.x); acc.y = fmaf(v0, x0.y, acc.y);
        acc.z = fmaf(v0, x0.z, acc.z); acc.w = fmaf(v0, x0.w, acc.w);
    }

    const float4 hb = *reinterpret_cast<const float4*>(h0 + (size_t)r * D + q * 4);
    float4 s;
    s.x = 0.9f * acc.x + 0.1f * hb.x;
    s.y = 0.9f * acc.y + 0.1f * hb.y;
    s.z = 0.9f * acc.z + 0.1f * hb.z;
    s.w = 0.9f * acc.w + 0.1f * hb.w;
    *reinterpret_cast<float4*>(S + (size_t)r * D + q * 4) = s;
}

// -------- Fallback K3 (atomic scatter) if workspace is too small ----------
__global__ __launch_bounds__(256) void spmm_atomic_kernel(const float* __restrict__ x,
                                                          const float* __restrict__ vals,
                                                          const int* __restrict__ rows,
                                                          const int* __restrict__ cols,
                                                          float* __restrict__ hi, int E) {
    int tid = blockIdx.x * blockDim.x + threadIdx.x;
    int e = tid >> 5;
    if (e >= E) return;
    int q = tid & 31;
    float v = vals[e];
    int c = cols[e];
    int r = rows[e];
    const float4 xv = *reinterpret_cast<const float4*>(x + (size_t)c * D + q * 4);
    float* h = hi + (size_t)r * D + q * 4;
    unsafeAtomicAdd(h + 0, v * xv.x);
    unsafeAtomicAdd(h + 1, v * xv.y);
    unsafeAtomicAdd(h + 2, v * xv.z);
    unsafeAtomicAdd(h + 3, v * xv.w);
}

__global__ __launch_bounds__(256) void blend_kernel(const float* __restrict__ hi,
                                                    const float* __restrict__ h0,
                                                    float* __restrict__ S, int nd4) {
    int i = blockIdx.x * blockDim.x + threadIdx.x;
    if (i >= nd4) return;
    float4 a = reinterpret_cast<const float4*>(hi)[i];
    float4 b = reinterpret_cast<const float4*>(h0)[i];
    float4 s;
    s.x = 0.9f * a.x + 0.1f * b.x;
    s.y = 0.9f * a.y + 0.1f * b.y;
    s.z = 0.9f * a.z + 0.1f * b.z;
    s.w = 0.9f * a.w + 0.1f * b.w;
    reinterpret_cast<float4*>(S)[i] = s;
}

// ---------------- K4: out = tanh(S @ M), 64 rows/block, 4x8/thread -------
__global__ __launch_bounds__(256) void gemm_tanh_kernel(const float* __restrict__ S,
                                                        const float* __restrict__ Mg,
                                                        float* __restrict__ out, int n) {
    __shared__ float Ms[64][D];        // 32 KiB: half of M (k-rows)
    __shared__ float Ss[RPB][D + 1];   // stride 129 conflict-free
    const int tid = threadIdx.x;
    const int r0  = blockIdx.x * RPB;

    for (int i = tid; i < RPB * D / 4; i += 256) {
        int rr = (i * 4) / D, cc = (i * 4) & (D - 1);
        int r = r0 + rr;
        float4 a = (r < n) ? *reinterpret_cast<const float4*>(S + (size_t)r * D + cc)
                           : make_float4(0.f, 0.f, 0.f, 0.f);
        Ss[rr][cc + 0] = a.x;
        Ss[rr][cc + 1] = a.y;
        Ss[rr][cc + 2] = a.z;
        Ss[rr][cc + 3] = a.w;
    }

    const int tc = tid & 15;
    const int tr = tid >> 4;
    float acc[4][8] = {};

    for (int kb = 0; kb < 2; ++kb) {
        __syncthreads();
        for (int i = tid; i < 64 * D / 4; i += 256)
            reinterpret_cast<float4*>(&Ms[0][0])[i] =
                reinterpret_cast<const float4*>(Mg + kb * 64 * D)[i];
        __syncthreads();
#pragma unroll 4
        for (int kk = 0; kk < 64; ++kk) {
            int k = kb * 64 + kk;
            float4 b0 = *reinterpret_cast<const float4*>(&Ms[kk][tc * 4]);
            float4 b1 = *reinterpret_cast<const float4*>(&Ms[kk][64 + tc * 4]);
#pragma unroll
            for (int m = 0; m < 4; ++m) {
                float a = Ss[4 * tr + m][k];
                acc[m][0] = fmaf(a, b0.x, acc[m][0]);
                acc[m][1] = fmaf(a, b0.y, acc[m][1]);
                acc[m][2] = fmaf(a, b0.z, acc[m][2]);
                acc[m][3] = fmaf(a, b0.w, acc[m][3]);
                acc[m][4] = fmaf(a, b1.x, acc[m][4]);
                acc[m][5] = fmaf(a, b1.y, acc[m][5]);
                acc[m][6] = fmaf(a, b1.z, acc[m][6]);
                acc[m][7] = fmaf(a, b1.w, acc[m][7]);
            }
        }
    }

#pragma unroll
    for (int m = 0; m < 4; ++m) {
        int r = r0 + 4 * tr + m;
        if (r >= n) continue;
        float4 o0, o1;
        o0.x = tanhf(acc[m][0]); o0.y = tanhf(acc[m][1]);
        o0.z = tanhf(acc[m][2]); o0.w = tanhf(acc[m][3]);
        o1.x = tanhf(acc[m][4]); o1.y = tanhf(acc[m][5]);
        o1.z = tanhf(acc[m][6]); o1.w = tanhf(acc[m][7]);
        *reinterpret_cast<float4*>(out + (size_t)r * D + tc * 4)      = o0;
        *reinterpret_cast<float4*>(out + (size_t)r * D + 64 + tc * 4) = o1;
    }
}

extern "C" void kernel_launch(void* const* d_in, const int* in_sizes, int n_in,
                              void* d_out, int out_size, void* d_ws, size_t ws_size,
                              hipStream_t stream) {
    const float* x  = (const float*)d_in[0];
    const float* h0 = (const float*)d_in[1];
    const float* W  = (const float*)d_in[2];
    const float* av = (const float*)d_in[3];
    const int*   ar = (const int*)d_in[4];
    const int*   ac = (const int*)d_in[5];
    const int*   lp = (const int*)d_in[6];
    float* out = (float*)d_out;

    const int nd = in_sizes[0];        // N*D
    const int n  = nd / D;             // N
    const int E  = in_sizes[3];

    char* wsb = (char*)d_ws;
    float* A  = (float*)wsb;                                   // D*D
    float* Lg = A + D * D;                                     // D*D
    float* Mg = Lg + D * D;                                    // D*D
    size_t off = 3 * (size_t)D * D * sizeof(float);

    int* rp = (int*)(wsb + off);                               // N ints
    off += (size_t)n * sizeof(int);
    off = (off + 15) & ~(size_t)15;
    uint2* csr = (uint2*)(wsb + off);                          // E uint2
    off += (size_t)E * sizeof(uint2);
    off = (off + 15) & ~(size_t)15;

    const size_t need_csr = off;
    const size_t need_S   = off + (size_t)nd * sizeof(float);
    const int gemm_grid = (n + RPB - 1) / RPB;

    if (ws_size >= need_csr) {
        float* S = (ws_size >= need_S) ? (float*)(wsb + off) : out;
        hipMemsetAsync(rp, 0, (size_t)n * sizeof(int), stream);
        hist_kernel<<<(E + 255) / 256, 256, 0, stream>>>(ar, rp, E);
        wtw_kernel<<<D * D / 256, 256, 0, stream>>>(W, A);
        scan_kernel<<<1, 1024, 0, stream>>>(rp, n);
        scatter_kernel<<<(E + 255) / 256, 256, 0, stream>>>(av, ar, ac, rp, csr, E);
        chol_factor_kernel<<<1, 256, 0, stream>>>(A, Lg);
        solve_m_kernel<<<D, 64, 0, stream>>>(Lg, W, lp, Mg);
        spmm_gather_kernel<<<(n + 7) / 8, 256, 0, stream>>>(x, h0, csr, rp, S, n);
        gemm_tanh_kernel<<<gemm_grid, 256, 0, stream>>>(S, Mg, out, n);
    } else {
        float* hi = out;
        hipMemsetAsync(hi, 0, (size_t)nd * sizeof(float), stream);
        wtw_kernel<<<D * D / 256, 256, 0, stream>>>(W, A);
        spmm_atomic_kernel<<<(int)(((size_t)E * 32 + 255) / 256), 256, 0, stream>>>(x, av, ar, ac, hi, E);
        chol_factor_kernel<<<1, 256, 0, stream>>>(A, Lg);
        solve_m_kernel<<<D, 64, 0, stream>>>(Lg, W, lp, Mg);
        blend_kernel<<<(nd / 4 + 255) / 256, 256, 0, stream>>>(hi, h0, hi, nd / 4);
        gemm_tanh_kernel<<<gemm_grid, 256, 0, stream>>>(hi, Mg, out, n);
    }
}

// Round 5
// 492.681 us; speedup vs baseline: 6.4869x; 1.3763x over previous
//
#include <hip/hip_runtime.h>
#include <math.h>

#define D 128
#define NB 16           // Cholesky panel width
#define RPB 64          // rows per block in the GEMM kernel
#define ALPHA 0.1f
#define LAMDA 0.5f

// ---------------- K1: A = W^T W + 1e-4 I  (tiny) ----------------
__global__ __launch_bounds__(256) void wtw_kernel(const float* __restrict__ W,
                                                  float* __restrict__ A) {
    int idx = blockIdx.x * blockDim.x + threadIdx.x;   // 16384 threads
    int i = idx >> 7, j = idx & (D - 1);
    float acc = (i == j) ? 1e-4f : 0.0f;
#pragma unroll 4
    for (int k = 0; k < D; ++k) acc = fmaf(W[k * D + i], W[k * D + j], acc);
    A[idx] = acc;
}

// ---------------- K2a: one-block BLOCKED Cholesky (NB=16) ----------------
__global__ __launch_bounds__(256) void chol_factor_kernel(const float* __restrict__ A_in,
                                                          float* __restrict__ Lg) {
    __shared__ float S[D][D];          // 64 KiB
    __shared__ float dinvS[NB];
    const int tid = threadIdx.x;
    const int tx = tid & 15;
    const int ty = tid >> 4;

    for (int i = tid; i < D * D; i += 256) ((float*)S)[i] = A_in[i];
    __syncthreads();

    for (int s = 0; s < D / NB; ++s) {
        const int b = s * NB;

        for (int k = 0; k < NB; ++k) {
            float dk  = S[b + k][b + k];
            float a_i = S[b + k][b + tx];
            float a_j = S[b + k][b + ty];
            float lkk  = sqrtf(dk);
            float inv  = 1.0f / lkk;
            float invd = inv * inv;
            __syncthreads();
            if (ty == 0) {
                if (tx == k)       { S[b + k][b + k] = lkk; dinvS[k] = inv; }
                else if (tx > k)     S[b + k][b + tx] = a_i * inv;
            }
            if (ty > k && tx >= ty)
                S[b + ty][b + tx] -= a_i * (a_j * invd);
            __syncthreads();
        }

        const int m = D - b - NB;

        if (m > 0 && tid < m) {
            const int r = b + NB + tid;
            float y[NB];
#pragma unroll
            for (int k = 0; k < NB; ++k) y[k] = S[b + k][r];
#pragma unroll
            for (int k = 0; k < NB; ++k) {
                float acc = y[k];
#pragma unroll
                for (int q = 0; q < NB; ++q)
                    if (q < k) acc -= S[b + q][b + k] * y[q];
                y[k] = acc * dinvS[k];
            }
#pragma unroll
            for (int k = 0; k < NB; ++k) S[b + k][r] = y[k];
        }
        __syncthreads();

        const int nt = m >> 4;
        for (int tc = 0; tc < nt; ++tc) {
            for (int tr = tc; tr < nt; ++tr) {
                const int c = b + NB + tc * 16 + ty;
                const int r = b + NB + tr * 16 + tx;
                if (r >= c) {
                    float acc = S[c][r];
#pragma unroll
                    for (int k = 0; k < NB; ++k)
                        acc -= S[b + k][r] * S[b + k][c];
                    S[c][r] = acc;
                }
            }
        }
        __syncthreads();
    }

    for (int i = tid; i < D * D; i += 256) Lg[i] = ((float*)S)[i];
}

// ---------------- K2b: parallel triangular solve + build M ---------------
__global__ __launch_bounds__(64) void solve_m_kernel(const float* __restrict__ Lg,
                                                     const float* __restrict__ W,
                                                     const int* __restrict__ lp,
                                                     float* __restrict__ Mg) {
    __shared__ float Lr[D][D + 1];
    const int lane = threadIdx.x;
    const int c = blockIdx.x;

    for (int j = 0; j < D; ++j) {
        Lr[lane][j]      = Lg[j * D + lane];
        Lr[lane + 64][j] = Lg[j * D + lane + 64];
    }
    __syncthreads();

    const float w_lo = W[c * D + lane];
    const float w_hi = W[c * D + 64 + lane];
    const float dinv_lo = 1.0f / Lr[lane][lane];
    const float dinv_hi = 1.0f / Lr[lane + 64][lane + 64];
    float y_lo = 0.0f, y_hi = 0.0f;

    for (int i = 0; i < D; ++i) {
        float l0 = Lr[i][lane];
        float l1 = Lr[i][lane + 64];
        float p = 0.0f;
        p += (lane < i)      ? l0 * y_lo : 0.0f;
        p += (lane + 64 < i) ? l1 * y_hi : 0.0f;
#pragma unroll
        for (int off = 32; off >= 1; off >>= 1) p += __shfl_xor(p, off);
        if (i < 64) {
            if (lane == i)      y_lo = (w_lo - p) * dinv_lo;
        } else {
            if (lane == i - 64) y_hi = (w_hi - p) * dinv_hi;
        }
    }

    const float th = logf(LAMDA / (float)(*lp) + 1.0f);
    float m_lo = th * y_lo + ((c == lane)      ? (1.0f - th) : 0.0f);
    float m_hi = th * y_hi + ((c == lane + 64) ? (1.0f - th) : 0.0f);
    Mg[c * D + lane]      = m_lo;
    Mg[c * D + 64 + lane] = m_hi;
}

// ---------------- CSR build: histogram -> 3-phase scan -> scatter --------
__global__ __launch_bounds__(256) void hist_kernel(const int* __restrict__ rows,
                                                   int* __restrict__ cnt, int E) {
    int e = blockIdx.x * blockDim.x + threadIdx.x;
    if (e < E) atomicAdd(&cnt[rows[e]], 1);
}

// Phase 1: per-block (1024 counts) sums.
__global__ __launch_bounds__(256) void scan_p1_kernel(const int* __restrict__ cnt,
                                                      int* __restrict__ bsum, int n) {
    const int tid = threadIdx.x;
    const int base = blockIdx.x * 1024 + tid * 4;
    int s = 0;
    if (base + 3 < n) {
        int4 v = *reinterpret_cast<const int4*>(cnt + base);
        s = v.x + v.y + v.z + v.w;
    } else {
        for (int j = 0; j < 4; ++j) if (base + j < n) s += cnt[base + j];
    }
#pragma unroll
    for (int off = 32; off >= 1; off >>= 1) s += __shfl_xor(s, off);
    __shared__ int wsum[4];
    if ((tid & 63) == 0) wsum[tid >> 6] = s;
    __syncthreads();
    if (tid == 0) bsum[blockIdx.x] = wsum[0] + wsum[1] + wsum[2] + wsum[3];
}

// Phase 2: one block exclusive-scans the block sums (nb can exceed 256).
__global__ __launch_bounds__(256) void scan_p2_kernel(int* __restrict__ bsum, int nb) {
    __shared__ int ps[256];
    const int tid = threadIdx.x;
    int carry = 0;
    for (int base = 0; base < nb; base += 256) {
        int idx = base + tid;
        int v = (idx < nb) ? bsum[idx] : 0;
        ps[tid] = v;
        __syncthreads();
        for (int off = 1; off < 256; off <<= 1) {
            int t = (tid >= off) ? ps[tid - off] : 0;
            __syncthreads();
            ps[tid] += t;
            __syncthreads();
        }
        if (idx < nb) bsum[idx] = carry + ps[tid] - v;   // exclusive
        int total = ps[255];
        __syncthreads();
        carry += total;
    }
}

// Phase 3: block-local exclusive scan + block offset, in place.
__global__ __launch_bounds__(256) void scan_p3_kernel(int* __restrict__ rp,
                                                      const int* __restrict__ bsum,
                                                      int n) {
    const int tid = threadIdx.x;
    const int lane = tid & 63;
    const int w = tid >> 6;
    const int base = blockIdx.x * 1024 + tid * 4;

    int4 v = make_int4(0, 0, 0, 0);
    if (base + 3 < n) {
        v = *reinterpret_cast<const int4*>(rp + base);
    } else {
        if (base + 0 < n) v.x = rp[base + 0];
        if (base + 1 < n) v.y = rp[base + 1];
        if (base + 2 < n) v.z = rp[base + 2];
        if (base + 3 < n) v.w = rp[base + 3];
    }
    int s = v.x + v.y + v.z + v.w;

    int inc = s;
#pragma unroll
    for (int off = 1; off < 64; off <<= 1) {
        int t = __shfl_up(inc, off);
        if (lane >= off) inc += t;
    }
    __shared__ int wsum[4];
    if (lane == 63) wsum[w] = inc;
    __syncthreads();
    int woff = 0;
    for (int i = 0; i < w; ++i) woff += wsum[i];

    int excl = bsum[blockIdx.x] + woff + inc - s;
    int4 o;
    o.x = excl;
    o.y = o.x + v.x;
    o.z = o.y + v.y;
    o.w = o.z + v.z;
    if (base + 3 < n) {
        *reinterpret_cast<int4*>(rp + base) = o;
    } else {
        if (base + 0 < n) rp[base + 0] = o.x;
        if (base + 1 < n) rp[base + 1] = o.y;
        if (base + 2 < n) rp[base + 2] = o.z;
        if (base + 3 < n) rp[base + 3] = o.w;
    }
}

// After scatter: rp[r] == end of row r; start == (r ? rp[r-1] : 0).
__global__ __launch_bounds__(256) void scatter_kernel(const float* __restrict__ vals,
                                                      const int* __restrict__ rows,
                                                      const int* __restrict__ cols,
                                                      int* __restrict__ rp,
                                                      uint2* __restrict__ csr, int E) {
    int e = blockIdx.x * blockDim.x + threadIdx.x;
    if (e >= E) return;
    int r = rows[e];
    int pos = atomicAdd(&rp[r], 1);
    uint2 p;
    p.x = (unsigned)cols[e];
    p.y = __float_as_uint(vals[e]);
    csr[pos] = p;
}

// ---------------- K3: gather SpMM + fused support scale ------------------
__global__ __launch_bounds__(256) void spmm_gather_kernel(const float* __restrict__ x,
                                                          const float* __restrict__ h0,
                                                          const uint2* __restrict__ csr,
                                                          const int* __restrict__ rp,
                                                          float* __restrict__ S, int n) {
    const int tid = threadIdx.x;
    const int r = blockIdx.x * 8 + (tid >> 5);
    if (r >= n) return;
    const int q = tid & 31;
    const int start = (r == 0) ? 0 : rp[r - 1];
    const int end = rp[r];

    float4 acc = make_float4(0.f, 0.f, 0.f, 0.f);
    int j = start;
    for (; j + 1 < end; j += 2) {
        uint2 p0 = csr[j];
        uint2 p1 = csr[j + 1];
        float v0 = __uint_as_float(p0.y);
        float v1 = __uint_as_float(p1.y);
        const float4 x0 = *reinterpret_cast<const float4*>(x + (size_t)p0.x * D + q * 4);
        const float4 x1 = *reinterpret_cast<const float4*>(x + (size_t)p1.x * D + q * 4);
        acc.x = fmaf(v0, x0.x, acc.x); acc.y = fmaf(v0, x0.y, acc.y);
        acc.z = fmaf(v0, x0.z, acc.z); acc.w = fmaf(v0, x0.w, acc.w);
        acc.x = fmaf(v1, x1.x, acc.x); acc.y = fmaf(v1, x1.y, acc.y);
        acc.z = fmaf(v1, x1.z, acc.z); acc.w = fmaf(v1, x1.w, acc.w);
    }
    if (j < end) {
        uint2 p0 = csr[j];
        float v0 = __uint_as_float(p0.y);
        const float4 x0 = *reinterpret_cast<const float4*>(x + (size_t)p0.x * D + q * 4);
        acc.x = fmaf(v0, x0.x, acc.x); acc.y = fmaf(v0, x0.y, acc.y);
        acc.z = fmaf(v0, x0.z, acc.z); acc.w = fmaf(v0, x0.w, acc.w);
    }

    const float4 hb = *reinterpret_cast<const float4*>(h0 + (size_t)r * D + q * 4);
    float4 s;
    s.x = 0.9f * acc.x + 0.1f * hb.x;
    s.y = 0.9f * acc.y + 0.1f * hb.y;
    s.z = 0.9f * acc.z + 0.1f * hb.z;
    s.w = 0.9f * acc.w + 0.1f * hb.w;
    *reinterpret_cast<float4*>(S + (size_t)r * D + q * 4) = s;
}

// -------- Fallback K3 (atomic scatter) if workspace is too small ----------
__global__ __launch_bounds__(256) void spmm_atomic_kernel(const float* __restrict__ x,
                                                          const float* __restrict__ vals,
                                                          const int* __restrict__ rows,
                                                          const int* __restrict__ cols,
                                                          float* __restrict__ hi, int E) {
    int tid = blockIdx.x * blockDim.x + threadIdx.x;
    int e = tid >> 5;
    if (e >= E) return;
    int q = tid & 31;
    float v = vals[e];
    int c = cols[e];
    int r = rows[e];
    const float4 xv = *reinterpret_cast<const float4*>(x + (size_t)c * D + q * 4);
    float* h = hi + (size_t)r * D + q * 4;
    unsafeAtomicAdd(h + 0, v * xv.x);
    unsafeAtomicAdd(h + 1, v * xv.y);
    unsafeAtomicAdd(h + 2, v * xv.z);
    unsafeAtomicAdd(h + 3, v * xv.w);
}

__global__ __launch_bounds__(256) void blend_kernel(const float* __restrict__ hi,
                                                    const float* __restrict__ h0,
                                                    float* __restrict__ S, int nd4) {
    int i = blockIdx.x * blockDim.x + threadIdx.x;
    if (i >= nd4) return;
    float4 a = reinterpret_cast<const float4*>(hi)[i];
    float4 b = reinterpret_cast<const float4*>(h0)[i];
    float4 s;
    s.x = 0.9f * a.x + 0.1f * b.x;
    s.y = 0.9f * a.y + 0.1f * b.y;
    s.z = 0.9f * a.z + 0.1f * b.z;
    s.w = 0.9f * a.w + 0.1f * b.w;
    reinterpret_cast<float4*>(S)[i] = s;
}

// ---------------- K4: out = tanh(S @ M), 64 rows/block, 4x8/thread -------
__global__ __launch_bounds__(256) void gemm_tanh_kernel(const float* __restrict__ S,
                                                        const float* __restrict__ Mg,
                                                        float* __restrict__ out, int n) {
    __shared__ float Ms[64][D];
    __shared__ float Ss[RPB][D + 1];
    const int tid = threadIdx.x;
    const int r0  = blockIdx.x * RPB;

    for (int i = tid; i < RPB * D / 4; i += 256) {
        int rr = (i * 4) / D, cc = (i * 4) & (D - 1);
        int r = r0 + rr;
        float4 a = (r < n) ? *reinterpret_cast<const float4*>(S + (size_t)r * D + cc)
                           : make_float4(0.f, 0.f, 0.f, 0.f);
        Ss[rr][cc + 0] = a.x;
        Ss[rr][cc + 1] = a.y;
        Ss[rr][cc + 2] = a.z;
        Ss[rr][cc + 3] = a.w;
    }

    const int tc = tid & 15;
    const int tr = tid >> 4;
    float acc[4][8] = {};

    for (int kb = 0; kb < 2; ++kb) {
        __syncthreads();
        for (int i = tid; i < 64 * D / 4; i += 256)
            reinterpret_cast<float4*>(&Ms[0][0])[i] =
                reinterpret_cast<const float4*>(Mg + kb * 64 * D)[i];
        __syncthreads();
#pragma unroll 4
        for (int kk = 0; kk < 64; ++kk) {
            int k = kb * 64 + kk;
            float4 b0 = *reinterpret_cast<const float4*>(&Ms[kk][tc * 4]);
            float4 b1 = *reinterpret_cast<const float4*>(&Ms[kk][64 + tc * 4]);
#pragma unroll
            for (int m = 0; m < 4; ++m) {
                float a = Ss[4 * tr + m][k];
                acc[m][0] = fmaf(a, b0.x, acc[m][0]);
                acc[m][1] = fmaf(a, b0.y, acc[m][1]);
                acc[m][2] = fmaf(a, b0.z, acc[m][2]);
                acc[m][3] = fmaf(a, b0.w, acc[m][3]);
                acc[m][4] = fmaf(a, b1.x, acc[m][4]);
                acc[m][5] = fmaf(a, b1.y, acc[m][5]);
                acc[m][6] = fmaf(a, b1.z, acc[m][6]);
                acc[m][7] = fmaf(a, b1.w, acc[m][7]);
            }
        }
    }

#pragma unroll
    for (int m = 0; m < 4; ++m) {
        int r = r0 + 4 * tr + m;
        if (r >= n) continue;
        float4 o0, o1;
        o0.x = tanhf(acc[m][0]); o0.y = tanhf(acc[m][1]);
        o0.z = tanhf(acc[m][2]); o0.w = tanhf(acc[m][3]);
        o1.x = tanhf(acc[m][4]); o1.y = tanhf(acc[m][5]);
        o1.z = tanhf(acc[m][6]); o1.w = tanhf(acc[m][7]);
        *reinterpret_cast<float4*>(out + (size_t)r * D + tc * 4)      = o0;
        *reinterpret_cast<float4*>(out + (size_t)r * D + 64 + tc * 4) = o1;
    }
}

extern "C" void kernel_launch(void* const* d_in, const int* in_sizes, int n_in,
                              void* d_out, int out_size, void* d_ws, size_t ws_size,
                              hipStream_t stream) {
    const float* x  = (const float*)d_in[0];
    const float* h0 = (const float*)d_in[1];
    const float* W  = (const float*)d_in[2];
    const float* av = (const float*)d_in[3];
    const int*   ar = (const int*)d_in[4];
    const int*   ac = (const int*)d_in[5];
    const int*   lp = (const int*)d_in[6];
    float* out = (float*)d_out;

    const int nd = in_sizes[0];        // N*D
    const int n  = nd / D;             // N
    const int E  = in_sizes[3];
    const int nb = (n + 1023) / 1024;  // scan blocks

    char* wsb = (char*)d_ws;
    float* A  = (float*)wsb;                                   // D*D
    float* Lg = A + D * D;                                     // D*D
    float* Mg = Lg + D * D;                                    // D*D
    size_t off = 3 * (size_t)D * D * sizeof(float);

    int* rp = (int*)(wsb + off);                               // N ints
    off += (size_t)n * sizeof(int);
    off = (off + 15) & ~(size_t)15;
    int* bsum = (int*)(wsb + off);                             // nb ints
    off += (size_t)nb * sizeof(int);
    off = (off + 15) & ~(size_t)15;
    uint2* csr = (uint2*)(wsb + off);                          // E uint2
    off += (size_t)E * sizeof(uint2);
    off = (off + 15) & ~(size_t)15;

    const size_t need_csr = off;
    const size_t need_S   = off + (size_t)nd * sizeof(float);
    const int gemm_grid = (n + RPB - 1) / RPB;

    if (ws_size >= need_csr) {
        float* S = (ws_size >= need_S) ? (float*)(wsb + off) : out;
        hipMemsetAsync(rp, 0, (size_t)n * sizeof(int), stream);
        hist_kernel<<<(E + 255) / 256, 256, 0, stream>>>(ar, rp, E);
        wtw_kernel<<<D * D / 256, 256, 0, stream>>>(W, A);
        scan_p1_kernel<<<nb, 256, 0, stream>>>(rp, bsum, n);
        scan_p2_kernel<<<1, 256, 0, stream>>>(bsum, nb);
        scan_p3_kernel<<<nb, 256, 0, stream>>>(rp, bsum, n);
        scatter_kernel<<<(E + 255) / 256, 256, 0, stream>>>(av, ar, ac, rp, csr, E);
        chol_factor_kernel<<<1, 256, 0, stream>>>(A, Lg);
        solve_m_kernel<<<D, 64, 0, stream>>>(Lg, W, lp, Mg);
        spmm_gather_kernel<<<(n + 7) / 8, 256, 0, stream>>>(x, h0, csr, rp, S, n);
        gemm_tanh_kernel<<<gemm_grid, 256, 0, stream>>>(S, Mg, out, n);
    } else {
        float* hi = out;
        hipMemsetAsync(hi, 0, (size_t)nd * sizeof(float), stream);
        wtw_kernel<<<D * D / 256, 256, 0, stream>>>(W, A);
        spmm_atomic_kernel<<<(int)(((size_t)E * 32 + 255) / 256), 256, 0, stream>>>(x, av, ar, ac, hi, E);
        chol_factor_kernel<<<1, 256, 0, stream>>>(A, Lg);
        solve_m_kernel<<<D, 64, 0, stream>>>(Lg, W, lp, Mg);
        blend_kernel<<<(nd / 4 + 255) / 256, 256, 0, stream>>>(hi, h0, hi, nd / 4);
        gemm_tanh_kernel<<<gemm_grid, 256, 0, stream>>>(hi, Mg, out, n);
    }
}

// Round 6
// 483.321 us; speedup vs baseline: 6.6126x; 1.0194x over previous
//
#include <hip/hip_runtime.h>
#include <math.h>

#define D 128
#define NB 16           // Cholesky panel width
#define RPB 64          // rows per block in the GEMM kernel
#define ALPHA 0.1f
#define LAMDA 0.5f

// ---------------- K1: A = W^T W + 1e-4 I  (tiny) ----------------
__global__ __launch_bounds__(256) void wtw_kernel(const float* __restrict__ W,
                                                  float* __restrict__ A) {
    int idx = blockIdx.x * blockDim.x + threadIdx.x;   // 16384 threads
    int i = idx >> 7, j = idx & (D - 1);
    float acc = (i == j) ? 1e-4f : 0.0f;
#pragma unroll 4
    for (int k = 0; k < D; ++k) acc = fmaf(W[k * D + i], W[k * D + j], acc);
    A[idx] = acc;
}

// ---------------- K2a: one-block BLOCKED Cholesky (NB=16) ----------------
__global__ __launch_bounds__(256) void chol_factor_kernel(const float* __restrict__ A_in,
                                                          float* __restrict__ Lg) {
    __shared__ float S[D][D];          // 64 KiB
    __shared__ float dinvS[NB];
    const int tid = threadIdx.x;
    const int tx = tid & 15;
    const int ty = tid >> 4;

    for (int i = tid; i < D * D; i += 256) ((float*)S)[i] = A_in[i];
    __syncthreads();

    for (int s = 0; s < D / NB; ++s) {
        const int b = s * NB;

        for (int k = 0; k < NB; ++k) {
            float dk  = S[b + k][b + k];
            float a_i = S[b + k][b + tx];
            float a_j = S[b + k][b + ty];
            float lkk  = sqrtf(dk);
            float inv  = 1.0f / lkk;
            float invd = inv * inv;
            __syncthreads();
            if (ty == 0) {
                if (tx == k)       { S[b + k][b + k] = lkk; dinvS[k] = inv; }
                else if (tx > k)     S[b + k][b + tx] = a_i * inv;
            }
            if (ty > k && tx >= ty)
                S[b + ty][b + tx] -= a_i * (a_j * invd);
            __syncthreads();
        }

        const int m = D - b - NB;

        if (m > 0 && tid < m) {
            const int r = b + NB + tid;
            float y[NB];
#pragma unroll
            for (int k = 0; k < NB; ++k) y[k] = S[b + k][r];
#pragma unroll
            for (int k = 0; k < NB; ++k) {
                float acc = y[k];
#pragma unroll
                for (int q = 0; q < NB; ++q)
                    if (q < k) acc -= S[b + q][b + k] * y[q];
                y[k] = acc * dinvS[k];
            }
#pragma unroll
            for (int k = 0; k < NB; ++k) S[b + k][r] = y[k];
        }
        __syncthreads();

        const int nt = m >> 4;
        for (int tc = 0; tc < nt; ++tc) {
            for (int tr = tc; tr < nt; ++tr) {
                const int c = b + NB + tc * 16 + ty;
                const int r = b + NB + tr * 16 + tx;
                if (r >= c) {
                    float acc = S[c][r];
#pragma unroll
                    for (int k = 0; k < NB; ++k)
                        acc -= S[b + k][r] * S[b + k][c];
                    S[c][r] = acc;
                }
            }
        }
        __syncthreads();
    }

    for (int i = tid; i < D * D; i += 256) Lg[i] = ((float*)S)[i];
}

// ---------------- K2b: parallel triangular solve + build M ---------------
__global__ __launch_bounds__(64) void solve_m_kernel(const float* __restrict__ Lg,
                                                     const float* __restrict__ W,
                                                     const int* __restrict__ lp,
                                                     float* __restrict__ Mg) {
    __shared__ float Lr[D][D + 1];
    const int lane = threadIdx.x;
    const int c = blockIdx.x;

    for (int j = 0; j < D; ++j) {
        Lr[lane][j]      = Lg[j * D + lane];
        Lr[lane + 64][j] = Lg[j * D + lane + 64];
    }
    __syncthreads();

    const float w_lo = W[c * D + lane];
    const float w_hi = W[c * D + 64 + lane];
    const float dinv_lo = 1.0f / Lr[lane][lane];
    const float dinv_hi = 1.0f / Lr[lane + 64][lane + 64];
    float y_lo = 0.0f, y_hi = 0.0f;

    for (int i = 0; i < D; ++i) {
        float l0 = Lr[i][lane];
        float l1 = Lr[i][lane + 64];
        float p = 0.0f;
        p += (lane < i)      ? l0 * y_lo : 0.0f;
        p += (lane + 64 < i) ? l1 * y_hi : 0.0f;
#pragma unroll
        for (int off = 32; off >= 1; off >>= 1) p += __shfl_xor(p, off);
        if (i < 64) {
            if (lane == i)      y_lo = (w_lo - p) * dinv_lo;
        } else {
            if (lane == i - 64) y_hi = (w_hi - p) * dinv_hi;
        }
    }

    const float th = logf(LAMDA / (float)(*lp) + 1.0f);
    float m_lo = th * y_lo + ((c == lane)      ? (1.0f - th) : 0.0f);
    float m_hi = th * y_hi + ((c == lane + 64) ? (1.0f - th) : 0.0f);
    Mg[c * D + lane]      = m_lo;
    Mg[c * D + 64 + lane] = m_hi;
}

// ---------------- x -> bf16 conversion (RNE) -----------------------------
__global__ __launch_bounds__(256) void cvt_bf16_kernel(const float* __restrict__ x,
                                                       unsigned short* __restrict__ xb,
                                                       int nd) {
    const int base = (blockIdx.x * 256 + threadIdx.x) * 8;
    if (base + 7 < nd) {
        float4 a = *reinterpret_cast<const float4*>(x + base);
        float4 b = *reinterpret_cast<const float4*>(x + base + 4);
        unsigned r[8];
        const float* f = &a.x;
#pragma unroll
        for (int i = 0; i < 4; ++i) {
            unsigned u = __float_as_uint(f[i]);
            r[i] = (u + 0x7FFFu + ((u >> 16) & 1u)) >> 16;
        }
        const float* g = &b.x;
#pragma unroll
        for (int i = 0; i < 4; ++i) {
            unsigned u = __float_as_uint(g[i]);
            r[4 + i] = (u + 0x7FFFu + ((u >> 16) & 1u)) >> 16;
        }
        uint4 o;
        o.x = r[0] | (r[1] << 16);
        o.y = r[2] | (r[3] << 16);
        o.z = r[4] | (r[5] << 16);
        o.w = r[6] | (r[7] << 16);
        *reinterpret_cast<uint4*>(xb + base) = o;
    } else {
        for (int i = 0; i < 8 && base + i < nd; ++i) {
            unsigned u = __float_as_uint(x[base + i]);
            xb[base + i] = (unsigned short)((u + 0x7FFFu + ((u >> 16) & 1u)) >> 16);
        }
    }
}

// ---------------- CSR build: histogram -> 3-phase scan -> scatter --------
__global__ __launch_bounds__(256) void hist_kernel(const int* __restrict__ rows,
                                                   int* __restrict__ cnt, int E) {
    int e = blockIdx.x * blockDim.x + threadIdx.x;
    if (e < E) atomicAdd(&cnt[rows[e]], 1);
}

__global__ __launch_bounds__(256) void scan_p1_kernel(const int* __restrict__ cnt,
                                                      int* __restrict__ bsum, int n) {
    const int tid = threadIdx.x;
    const int base = blockIdx.x * 1024 + tid * 4;
    int s = 0;
    if (base + 3 < n) {
        int4 v = *reinterpret_cast<const int4*>(cnt + base);
        s = v.x + v.y + v.z + v.w;
    } else {
        for (int j = 0; j < 4; ++j) if (base + j < n) s += cnt[base + j];
    }
#pragma unroll
    for (int off = 32; off >= 1; off >>= 1) s += __shfl_xor(s, off);
    __shared__ int wsum[4];
    if ((tid & 63) == 0) wsum[tid >> 6] = s;
    __syncthreads();
    if (tid == 0) bsum[blockIdx.x] = wsum[0] + wsum[1] + wsum[2] + wsum[3];
}

__global__ __launch_bounds__(256) void scan_p2_kernel(int* __restrict__ bsum, int nb) {
    __shared__ int ps[256];
    const int tid = threadIdx.x;
    int carry = 0;
    for (int base = 0; base < nb; base += 256) {
        int idx = base + tid;
        int v = (idx < nb) ? bsum[idx] : 0;
        ps[tid] = v;
        __syncthreads();
        for (int off = 1; off < 256; off <<= 1) {
            int t = (tid >= off) ? ps[tid - off] : 0;
            __syncthreads();
            ps[tid] += t;
            __syncthreads();
        }
        if (idx < nb) bsum[idx] = carry + ps[tid] - v;
        int total = ps[255];
        __syncthreads();
        carry += total;
    }
}

__global__ __launch_bounds__(256) void scan_p3_kernel(int* __restrict__ rp,
                                                      const int* __restrict__ bsum,
                                                      int n) {
    const int tid = threadIdx.x;
    const int lane = tid & 63;
    const int w = tid >> 6;
    const int base = blockIdx.x * 1024 + tid * 4;

    int4 v = make_int4(0, 0, 0, 0);
    if (base + 3 < n) {
        v = *reinterpret_cast<const int4*>(rp + base);
    } else {
        if (base + 0 < n) v.x = rp[base + 0];
        if (base + 1 < n) v.y = rp[base + 1];
        if (base + 2 < n) v.z = rp[base + 2];
        if (base + 3 < n) v.w = rp[base + 3];
    }
    int s = v.x + v.y + v.z + v.w;

    int inc = s;
#pragma unroll
    for (int off = 1; off < 64; off <<= 1) {
        int t = __shfl_up(inc, off);
        if (lane >= off) inc += t;
    }
    __shared__ int wsum[4];
    if (lane == 63) wsum[w] = inc;
    __syncthreads();
    int woff = 0;
    for (int i = 0; i < w; ++i) woff += wsum[i];

    int excl = bsum[blockIdx.x] + woff + inc - s;
    int4 o;
    o.x = excl;
    o.y = o.x + v.x;
    o.z = o.y + v.y;
    o.w = o.z + v.z;
    if (base + 3 < n) {
        *reinterpret_cast<int4*>(rp + base) = o;
    } else {
        if (base + 0 < n) rp[base + 0] = o.x;
        if (base + 1 < n) rp[base + 1] = o.y;
        if (base + 2 < n) rp[base + 2] = o.z;
        if (base + 3 < n) rp[base + 3] = o.w;
    }
}

// After scatter: rp[r] == end of row r; start == (r ? rp[r-1] : 0).
__global__ __launch_bounds__(256) void scatter_kernel(const float* __restrict__ vals,
                                                      const int* __restrict__ rows,
                                                      const int* __restrict__ cols,
                                                      int* __restrict__ rp,
                                                      uint2* __restrict__ csr, int E) {
    int e = blockIdx.x * blockDim.x + threadIdx.x;
    if (e >= E) return;
    int r = rows[e];
    int pos = atomicAdd(&rp[r], 1);
    uint2 p;
    p.x = (unsigned)cols[e];
    p.y = __float_as_uint(vals[e]);
    csr[pos] = p;
}

// ---------------- K3: bf16 gather SpMM + fused support scale -------------
// 16 lanes per row, 16 B/lane (8 bf16). S[r] = 0.9*sum v*x[c] + 0.1*h0[r].
__global__ __launch_bounds__(256) void spmm_gather_bf16_kernel(
        const unsigned short* __restrict__ xb,
        const float* __restrict__ h0,
        const uint2* __restrict__ csr,
        const int* __restrict__ rp,
        float* __restrict__ S, int n) {
    const int tid = threadIdx.x;
    const int r = blockIdx.x * 16 + (tid >> 4);
    if (r >= n) return;
    const int q = tid & 15;            // elems 8q .. 8q+7
    const int start = (r == 0) ? 0 : rp[r - 1];
    const int end = rp[r];

    float acc[8] = {};
    int j = start;
    for (; j + 1 < end; j += 2) {
        uint2 p0 = csr[j];
        uint2 p1 = csr[j + 1];
        float v0 = __uint_as_float(p0.y);
        float v1 = __uint_as_float(p1.y);
        uint4 a = *reinterpret_cast<const uint4*>(xb + (size_t)p0.x * D + q * 8);
        uint4 b = *reinterpret_cast<const uint4*>(xb + (size_t)p1.x * D + q * 8);
        const unsigned* aw = &a.x;
        const unsigned* bw = &b.x;
#pragma unroll
        for (int t = 0; t < 4; ++t) {
            float alo = __uint_as_float(aw[t] << 16);
            float ahi = __uint_as_float(aw[t] & 0xffff0000u);
            acc[2 * t]     = fmaf(v0, alo, acc[2 * t]);
            acc[2 * t + 1] = fmaf(v0, ahi, acc[2 * t + 1]);
            float blo = __uint_as_float(bw[t] << 16);
            float bhi = __uint_as_float(bw[t] & 0xffff0000u);
            acc[2 * t]     = fmaf(v1, blo, acc[2 * t]);
            acc[2 * t + 1] = fmaf(v1, bhi, acc[2 * t + 1]);
        }
    }
    if (j < end) {
        uint2 p0 = csr[j];
        float v0 = __uint_as_float(p0.y);
        uint4 a = *reinterpret_cast<const uint4*>(xb + (size_t)p0.x * D + q * 8);
        const unsigned* aw = &a.x;
#pragma unroll
        for (int t = 0; t < 4; ++t) {
            float alo = __uint_as_float(aw[t] << 16);
            float ahi = __uint_as_float(aw[t] & 0xffff0000u);
            acc[2 * t]     = fmaf(v0, alo, acc[2 * t]);
            acc[2 * t + 1] = fmaf(v0, ahi, acc[2 * t + 1]);
        }
    }

    const float4 hb0 = *reinterpret_cast<const float4*>(h0 + (size_t)r * D + q * 8);
    const float4 hb1 = *reinterpret_cast<const float4*>(h0 + (size_t)r * D + q * 8 + 4);
    float4 s0, s1;
    s0.x = 0.9f * acc[0] + 0.1f * hb0.x;
    s0.y = 0.9f * acc[1] + 0.1f * hb0.y;
    s0.z = 0.9f * acc[2] + 0.1f * hb0.z;
    s0.w = 0.9f * acc[3] + 0.1f * hb0.w;
    s1.x = 0.9f * acc[4] + 0.1f * hb1.x;
    s1.y = 0.9f * acc[5] + 0.1f * hb1.y;
    s1.z = 0.9f * acc[6] + 0.1f * hb1.z;
    s1.w = 0.9f * acc[7] + 0.1f * hb1.w;
    *reinterpret_cast<float4*>(S + (size_t)r * D + q * 8)     = s0;
    *reinterpret_cast<float4*>(S + (size_t)r * D + q * 8 + 4) = s1;
}

// ---------------- K3 (f32 gather, fallback when no room for xb) ----------
__global__ __launch_bounds__(256) void spmm_gather_kernel(const float* __restrict__ x,
                                                          const float* __restrict__ h0,
                                                          const uint2* __restrict__ csr,
                                                          const int* __restrict__ rp,
                                                          float* __restrict__ S, int n) {
    const int tid = threadIdx.x;
    const int r = blockIdx.x * 8 + (tid >> 5);
    if (r >= n) return;
    const int q = tid & 31;
    const int start = (r == 0) ? 0 : rp[r - 1];
    const int end = rp[r];

    float4 acc = make_float4(0.f, 0.f, 0.f, 0.f);
    int j = start;
    for (; j + 1 < end; j += 2) {
        uint2 p0 = csr[j];
        uint2 p1 = csr[j + 1];
        float v0 = __uint_as_float(p0.y);
        float v1 = __uint_as_float(p1.y);
        const float4 x0 = *reinterpret_cast<const float4*>(x + (size_t)p0.x * D + q * 4);
        const float4 x1 = *reinterpret_cast<const float4*>(x + (size_t)p1.x * D + q * 4);
        acc.x = fmaf(v0, x0.x, acc.x); acc.y = fmaf(v0, x0.y, acc.y);
        acc.z = fmaf(v0, x0.z, acc.z); acc.w = fmaf(v0, x0.w, acc.w);
        acc.x = fmaf(v1, x1.x, acc.x); acc.y = fmaf(v1, x1.y, acc.y);
        acc.z = fmaf(v1, x1.z, acc.z); acc.w = fmaf(v1, x1.w, acc.w);
    }
    if (j < end) {
        uint2 p0 = csr[j];
        float v0 = __uint_as_float(p0.y);
        const float4 x0 = *reinterpret_cast<const float4*>(x + (size_t)p0.x * D + q * 4);
        acc.x = fmaf(v0, x0.x, acc.x); acc.y = fmaf(v0, x0.y, acc.y);
        acc.z = fmaf(v0, x0.z, acc.z); acc.w = fmaf(v0, x0.w, acc.w);
    }

    const float4 hb = *reinterpret_cast<const float4*>(h0 + (size_t)r * D + q * 4);
    float4 s;
    s.x = 0.9f * acc.x + 0.1f * hb.x;
    s.y = 0.9f * acc.y + 0.1f * hb.y;
    s.z = 0.9f * acc.z + 0.1f * hb.z;
    s.w = 0.9f * acc.w + 0.1f * hb.w;
    *reinterpret_cast<float4*>(S + (size_t)r * D + q * 4) = s;
}

// -------- Fallback K3 (atomic scatter) if workspace is too small ----------
__global__ __launch_bounds__(256) void spmm_atomic_kernel(const float* __restrict__ x,
                                                          const float* __restrict__ vals,
                                                          const int* __restrict__ rows,
                                                          const int* __restrict__ cols,
                                                          float* __restrict__ hi, int E) {
    int tid = blockIdx.x * blockDim.x + threadIdx.x;
    int e = tid >> 5;
    if (e >= E) return;
    int q = tid & 31;
    float v = vals[e];
    int c = cols[e];
    int r = rows[e];
    const float4 xv = *reinterpret_cast<const float4*>(x + (size_t)c * D + q * 4);
    float* h = hi + (size_t)r * D + q * 4;
    unsafeAtomicAdd(h + 0, v * xv.x);
    unsafeAtomicAdd(h + 1, v * xv.y);
    unsafeAtomicAdd(h + 2, v * xv.z);
    unsafeAtomicAdd(h + 3, v * xv.w);
}

__global__ __launch_bounds__(256) void blend_kernel(const float* __restrict__ hi,
                                                    const float* __restrict__ h0,
                                                    float* __restrict__ S, int nd4) {
    int i = blockIdx.x * blockDim.x + threadIdx.x;
    if (i >= nd4) return;
    float4 a = reinterpret_cast<const float4*>(hi)[i];
    float4 b = reinterpret_cast<const float4*>(h0)[i];
    float4 s;
    s.x = 0.9f * a.x + 0.1f * b.x;
    s.y = 0.9f * a.y + 0.1f * b.y;
    s.z = 0.9f * a.z + 0.1f * b.z;
    s.w = 0.9f * a.w + 0.1f * b.w;
    reinterpret_cast<float4*>(S)[i] = s;
}

// ---------------- K4: out = tanh(S @ M), 64 rows/block, 4x8/thread -------
__global__ __launch_bounds__(256) void gemm_tanh_kernel(const float* __restrict__ S,
                                                        const float* __restrict__ Mg,
                                                        float* __restrict__ out, int n) {
    __shared__ float Ms[64][D];
    __shared__ float Ss[RPB][D + 1];
    const int tid = threadIdx.x;
    const int r0  = blockIdx.x * RPB;

    for (int i = tid; i < RPB * D / 4; i += 256) {
        int rr = (i * 4) / D, cc = (i * 4) & (D - 1);
        int r = r0 + rr;
        float4 a = (r < n) ? *reinterpret_cast<const float4*>(S + (size_t)r * D + cc)
                           : make_float4(0.f, 0.f, 0.f, 0.f);
        Ss[rr][cc + 0] = a.x;
        Ss[rr][cc + 1] = a.y;
        Ss[rr][cc + 2] = a.z;
        Ss[rr][cc + 3] = a.w;
    }

    const int tc = tid & 15;
    const int tr = tid >> 4;
    float acc[4][8] = {};

    for (int kb = 0; kb < 2; ++kb) {
        __syncthreads();
        for (int i = tid; i < 64 * D / 4; i += 256)
            reinterpret_cast<float4*>(&Ms[0][0])[i] =
                reinterpret_cast<const float4*>(Mg + kb * 64 * D)[i];
        __syncthreads();
#pragma unroll 4
        for (int kk = 0; kk < 64; ++kk) {
            int k = kb * 64 + kk;
            float4 b0 = *reinterpret_cast<const float4*>(&Ms[kk][tc * 4]);
            float4 b1 = *reinterpret_cast<const float4*>(&Ms[kk][64 + tc * 4]);
#pragma unroll
            for (int m = 0; m < 4; ++m) {
                float a = Ss[4 * tr + m][k];
                acc[m][0] = fmaf(a, b0.x, acc[m][0]);
                acc[m][1] = fmaf(a, b0.y, acc[m][1]);
                acc[m][2] = fmaf(a, b0.z, acc[m][2]);
                acc[m][3] = fmaf(a, b0.w, acc[m][3]);
                acc[m][4] = fmaf(a, b1.x, acc[m][4]);
                acc[m][5] = fmaf(a, b1.y, acc[m][5]);
                acc[m][6] = fmaf(a, b1.z, acc[m][6]);
                acc[m][7] = fmaf(a, b1.w, acc[m][7]);
            }
        }
    }

#pragma unroll
    for (int m = 0; m < 4; ++m) {
        int r = r0 + 4 * tr + m;
        if (r >= n) continue;
        float4 o0, o1;
        o0.x = tanhf(acc[m][0]); o0.y = tanhf(acc[m][1]);
        o0.z = tanhf(acc[m][2]); o0.w = tanhf(acc[m][3]);
        o1.x = tanhf(acc[m][4]); o1.y = tanhf(acc[m][5]);
        o1.z = tanhf(acc[m][6]); o1.w = tanhf(acc[m][7]);
        *reinterpret_cast<float4*>(out + (size_t)r * D + tc * 4)      = o0;
        *reinterpret_cast<float4*>(out + (size_t)r * D + 64 + tc * 4) = o1;
    }
}

extern "C" void kernel_launch(void* const* d_in, const int* in_sizes, int n_in,
                              void* d_out, int out_size, void* d_ws, size_t ws_size,
                              hipStream_t stream) {
    const float* x  = (const float*)d_in[0];
    const float* h0 = (const float*)d_in[1];
    const float* W  = (const float*)d_in[2];
    const float* av = (const float*)d_in[3];
    const int*   ar = (const int*)d_in[4];
    const int*   ac = (const int*)d_in[5];
    const int*   lp = (const int*)d_in[6];
    float* out = (float*)d_out;

    const int nd = in_sizes[0];        // N*D
    const int n  = nd / D;             // N
    const int E  = in_sizes[3];
    const int nb = (n + 1023) / 1024;  // scan blocks

    char* wsb = (char*)d_ws;
    float* A  = (float*)wsb;                                   // D*D
    float* Lg = A + D * D;                                     // D*D
    float* Mg = Lg + D * D;                                    // D*D
    size_t off = 3 * (size_t)D * D * sizeof(float);

    int* rp = (int*)(wsb + off);                               // N ints
    off += (size_t)n * sizeof(int);
    off = (off + 15) & ~(size_t)15;
    int* bsum = (int*)(wsb + off);                             // nb ints
    off += (size_t)nb * sizeof(int);
    off = (off + 15) & ~(size_t)15;
    uint2* csr = (uint2*)(wsb + off);                          // E uint2
    off += (size_t)E * sizeof(uint2);
    off = (off + 15) & ~(size_t)15;
    const size_t need_csr = off;

    unsigned short* xb = (unsigned short*)(wsb + off);         // nd bf16
    size_t off_xb = off + (size_t)nd * sizeof(unsigned short);
    off_xb = (off_xb + 15) & ~(size_t)15;

    const size_t need_xb   = off_xb;                           // csr + xb
    const size_t need_S_f32 = need_csr + (size_t)nd * sizeof(float);
    const size_t need_S_b16 = need_xb + (size_t)nd * sizeof(float);
    const int gemm_grid = (n + RPB - 1) / RPB;

    if (ws_size >= need_xb) {
        float* S = (ws_size >= need_S_b16) ? (float*)(wsb + off_xb) : out;
        hipMemsetAsync(rp, 0, (size_t)n * sizeof(int), stream);
        hist_kernel<<<(E + 255) / 256, 256, 0, stream>>>(ar, rp, E);
        cvt_bf16_kernel<<<(nd / 8 + 255) / 256, 256, 0, stream>>>(x, xb, nd);
        wtw_kernel<<<D * D / 256, 256, 0, stream>>>(W, A);
        scan_p1_kernel<<<nb, 256, 0, stream>>>(rp, bsum, n);
        scan_p2_kernel<<<1, 256, 0, stream>>>(bsum, nb);
        scan_p3_kernel<<<nb, 256, 0, stream>>>(rp, bsum, n);
        scatter_kernel<<<(E + 255) / 256, 256, 0, stream>>>(av, ar, ac, rp, csr, E);
        chol_factor_kernel<<<1, 256, 0, stream>>>(A, Lg);
        solve_m_kernel<<<D, 64, 0, stream>>>(Lg, W, lp, Mg);
        spmm_gather_bf16_kernel<<<(n + 15) / 16, 256, 0, stream>>>(xb, h0, csr, rp, S, n);
        gemm_tanh_kernel<<<gemm_grid, 256, 0, stream>>>(S, Mg, out, n);
    } else if (ws_size >= need_csr) {
        float* S = (ws_size >= need_S_f32) ? (float*)(wsb + need_csr) : out;
        hipMemsetAsync(rp, 0, (size_t)n * sizeof(int), stream);
        hist_kernel<<<(E + 255) / 256, 256, 0, stream>>>(ar, rp, E);
        wtw_kernel<<<D * D / 256, 256, 0, stream>>>(W, A);
        scan_p1_kernel<<<nb, 256, 0, stream>>>(rp, bsum, n);
        scan_p2_kernel<<<1, 256, 0, stream>>>(bsum, nb);
        scan_p3_kernel<<<nb, 256, 0, stream>>>(rp, bsum, n);
        scatter_kernel<<<(E + 255) / 256, 256, 0, stream>>>(av, ar, ac, rp, csr, E);
        chol_factor_kernel<<<1, 256, 0, stream>>>(A, Lg);
        solve_m_kernel<<<D, 64, 0, stream>>>(Lg, W, lp, Mg);
        spmm_gather_kernel<<<(n + 7) / 8, 256, 0, stream>>>(x, h0, csr, rp, S, n);
        gemm_tanh_kernel<<<gemm_grid, 256, 0, stream>>>(S, Mg, out, n);
    } else {
        float* hi = out;
        hipMemsetAsync(hi, 0, (size_t)nd * sizeof(float), stream);
        wtw_kernel<<<D * D / 256, 256, 0, stream>>>(W, A);
        spmm_atomic_kernel<<<(int)(((size_t)E * 32 + 255) / 256), 256, 0, stream>>>(x, av, ar, ac, hi, E);
        chol_factor_kernel<<<1, 256, 0, stream>>>(A, Lg);
        solve_m_kernel<<<D, 64, 0, stream>>>(Lg, W, lp, Mg);
        blend_kernel<<<(nd / 4 + 255) / 256, 256, 0, stream>>>(hi, h0, hi, nd / 4);
        gemm_tanh_kernel<<<gemm_grid, 256, 0, stream>>>(hi, Mg, out, n);
    }
}